// Round 6
// baseline (509.547 us; speedup 1.0000x reference)
//
#include <hip/hip_runtime.h>
#include <hip/hip_bf16.h>
#include <math.h>

typedef unsigned short ushort_t;
typedef short short8 __attribute__((ext_vector_type(8)));
typedef float f32x4 __attribute__((ext_vector_type(4)));

#define N_TOK 512
#define EMBED 1024
#define INTER 4096
#define NCAT  5120   /* INTER + EMBED */
#define MROWS 24576  /* 48 * 512 */

__device__ __forceinline__ ushort_t f2bf(float f) {
  union { float f; unsigned int u; } c; c.f = f;
  unsigned int u = c.u;
  unsigned int r = u + 0x7fffu + ((u >> 16) & 1u);
  return (ushort_t)(r >> 16);
}

__device__ __forceinline__ void gld_lds16(const void* g, void* l) {
  __builtin_amdgcn_global_load_lds(
      (const __attribute__((address_space(1))) void*)g,
      (__attribute__((address_space(3))) void*)l, 16, 0, 0);
}

// ---- prep kernels -------------------------------------------------------

__global__ void prep_bcat(const float* __restrict__ bl, const float* __restrict__ br,
                          float* __restrict__ dst) {
  int i = blockIdx.x * 256 + threadIdx.x;
  if (i >= NCAT) return;
  dst[i] = (i < INTER) ? bl[i] : br[i - INTER];
}

__global__ void prep_wout(const float* __restrict__ W, ushort_t* __restrict__ dst) {
  int i = blockIdx.x * 256 + threadIdx.x;   // total EMBED*INTER, exact grid
  dst[i] = f2bf(W[i]);
}

__global__ void prep_wcat(const float* __restrict__ Wl, const float* __restrict__ Wr,
                          ushort_t* __restrict__ dst, int P3, int Kpad) {
  int i = blockIdx.x * 256 + threadIdx.x;
  int total = NCAT * Kpad;
  if (i >= total) return;
  int r = i / Kpad, j = i - r * Kpad;
  float v = 0.f;
  if (j < P3) {
    float scale = 96.0f / (float)P3;
    float src = (j + 0.5f) * scale - 0.5f;
    src = fminf(fmaxf(src, 0.0f), 95.0f);
    int i0 = (int)src;
    int i1 = min(i0 + 1, 95);
    float tt = src - (float)i0;
    const float* Wrow = (r < INTER) ? (Wl + (size_t)r * 96)
                                    : (Wr + (size_t)(r - INTER) * 96);
    v = Wrow[i0] * (1.f - tt) + Wrow[i1] * tt;
  }
  dst[i] = f2bf(v);
}

__global__ void prep_xs(const float* __restrict__ x, const float* __restrict__ m,
                        const float* __restrict__ t, ushort_t* __restrict__ dst,
                        int p, int Kpad) {
  int i = blockIdx.x * 256 + threadIdx.x;
  int total = 8192 * Kpad;
  if (i >= total) return;
  int r = i / Kpad, j = i - r * Kpad;
  float v = 0.f;
  int p3 = 3 * p;
  if (j < p3) {
    size_t base = (size_t)r * p;
    if (j < p)           v = x[base + j];
    else if (j < 2 * p)  v = m[base + j - p];
    else                 v = t[base + j - 2 * p];
  }
  dst[i] = f2bf(v);
}

// ---- phase-1: 128x128 GEMM (R3 structure, proven) -----------------------
__global__ __launch_bounds__(256)
void gemm128p1(const ushort_t* __restrict__ A, const ushort_t* __restrict__ B,
               int Kpad, const float* __restrict__ bias,
               ushort_t* __restrict__ hidden, float* __restrict__ outp,
               const int* __restrict__ idxg) {
  __shared__ __align__(16) ushort_t lA[2][128 * 32];
  __shared__ __align__(16) ushort_t lB[2][128 * 32];
  const int t = threadIdx.x;
  const int wave = t >> 6, lane = t & 63;
  const int tm = blockIdx.x * 128, tn = blockIdx.y * 128;

  const int chunk = wave * 2;
  const int srow = chunk * 16 + (lane >> 2);
  const int scol = (((lane & 3) ^ ((lane >> 3) & 3)) * 8);
  const ushort_t* gA0 = A + (size_t)(tm + srow) * Kpad + scol;
  const ushort_t* gA1 = gA0 + (size_t)16 * Kpad;
  const ushort_t* gB0 = B + (size_t)(tn + srow) * Kpad + scol;
  const ushort_t* gB1 = gB0 + (size_t)16 * Kpad;
  const int ldsOff0 = chunk * 512;
  const int ldsOff1 = ldsOff0 + 512;

  const int wr = wave >> 1, wc = wave & 1;
  const f32x4 zero = {0.f, 0.f, 0.f, 0.f};
  f32x4 acc[4][4];
#pragma unroll
  for (int m2 = 0; m2 < 4; ++m2)
#pragma unroll
    for (int n2 = 0; n2 < 4; ++n2) acc[m2][n2] = zero;

  const int xf = ((lane & 15) >> 1) & 3;
  const int fcol = (((lane >> 4) ^ xf)) * 8;
  const int aoff = (wr * 64 + (lane & 15)) * 32 + fcol;
  const int boff = (wc * 64 + (lane & 15)) * 32 + fcol;

  const int nk = Kpad >> 5;
  gld_lds16(gA0, &lA[0][ldsOff0]); gld_lds16(gA1, &lA[0][ldsOff1]);
  gld_lds16(gB0, &lB[0][ldsOff0]); gld_lds16(gB1, &lB[0][ldsOff1]);
  gA0 += 32; gA1 += 32; gB0 += 32; gB1 += 32;

  for (int kk = 0; kk < nk; ++kk) {
    const int cur = kk & 1;
    if (kk + 1 < nk) {
      const int nxt = cur ^ 1;
      gld_lds16(gA0, &lA[nxt][ldsOff0]); gld_lds16(gA1, &lA[nxt][ldsOff1]);
      gld_lds16(gB0, &lB[nxt][ldsOff0]); gld_lds16(gB1, &lB[nxt][ldsOff1]);
      gA0 += 32; gA1 += 32; gB0 += 32; gB1 += 32;
      asm volatile("s_waitcnt vmcnt(4)" ::: "memory");
    } else {
      asm volatile("s_waitcnt vmcnt(0)" ::: "memory");
    }
    __builtin_amdgcn_s_barrier();
    asm volatile("" ::: "memory");

    const ushort_t* pa = &lA[cur][0] + aoff;
    const ushort_t* pb = &lB[cur][0] + boff;
    short8 aF[4], bF[4];
#pragma unroll
    for (int m2 = 0; m2 < 4; ++m2) aF[m2] = *(const short8*)(pa + m2 * 16 * 32);
#pragma unroll
    for (int n2 = 0; n2 < 4; ++n2) bF[n2] = *(const short8*)(pb + n2 * 16 * 32);
#pragma unroll
    for (int m2 = 0; m2 < 4; ++m2)
#pragma unroll
      for (int n2 = 0; n2 < 4; ++n2)
        acc[m2][n2] = __builtin_amdgcn_mfma_f32_16x16x32_bf16(
            aF[m2], bF[n2], acc[m2][n2], 0, 0, 0);
    __builtin_amdgcn_s_barrier();
    asm volatile("" ::: "memory");
  }

  const int layer = idxg[tm >> 9];
  const int rowBase = layer * N_TOK + (tm & (N_TOK - 1));

#pragma unroll
  for (int m2 = 0; m2 < 4; ++m2) {
#pragma unroll
    for (int n2 = 0; n2 < 4; ++n2) {
      const int colg = tn + wc * 64 + n2 * 16 + (lane & 15);
      const float bv = bias[colg];
#pragma unroll
      for (int r = 0; r < 4; ++r) {
        const int rowl = wr * 64 + m2 * 16 + (lane >> 4) * 4 + r;
        const float v = acc[m2][n2][r];
        const int grow = rowBase + rowl;
        if (colg < INTER) {
          float h = v + bv;
          h = h / (1.f + expf(-h));
          hidden[(size_t)grow * INTER + colg] = f2bf(h);
        } else {
          outp[(size_t)grow * EMBED + (colg - INTER)] = v + bv;
        }
      }
    }
  }
}

// ---- phase-2: 256x256x(K/2) half-step pipelined GEMM -------------------
// Same geometry/swizzle/ledger data as R5, but the per-phase barrier
// lockstep is replaced by 2 fence-free half-steps per iteration: all 24
// fragment ds_reads + 64 MFMAs of one K-tile live in one region so the
// compiler software-pipelines them (counted lgkmcnt per quadrant), then
// [lgkm(0) + sched_barrier + s_barrier] (read-done, WAR-safe), restage the
// same buffer with the K-tile 2 ahead, counted vmcnt(8), barrier.
// FIFO invariant at each half boundary: [prev-KT(8), newly-staged-KT(8)]
// -> vmcnt(8) drains exactly the K-tile needed next.
#define RA0 0
#define RA1 16384
#define RB0 32768
#define RB1 49152
#define BUF1 65536

__global__ __launch_bounds__(512, 2)
void gemm256k(const ushort_t* __restrict__ A, const ushort_t* __restrict__ Bw,
              const float* __restrict__ bias, float* __restrict__ outp) {
  __shared__ __align__(16) char smem[131072];
  const int tid = threadIdx.x;
  const int w = tid >> 6, l = tid & 63;

  const int L = blockIdx.x;
  const int xcd = L & 7, j = L >> 3;
  const int nt = j & 3, kh = (j >> 2) & 1, mtl = j >> 3;
  const int mt = xcd * 12 + mtl;
  const int tm = mt * 256, tn = nt * 256;
  const int kbase = kh * 2048;

  // staging source pointers (pre-swizzled global, linear LDS dest)
  const ushort_t* pA0[2]; const ushort_t* pA1[2];
  const ushort_t* pB0[2]; const ushort_t* pB1[2];
  int dstq[2];
#pragma unroll
  for (int jj = 0; jj < 2; ++jj) {
    const int q = w * 2 + jj;                 // 0..15
    const int ks = q >> 3;
    const int hr = (q & 7) * 16 + (l >> 2);   // HT row 0..127
    const int c = (l & 3) ^ ((hr >> 1) & 3);  // source chunk (inverse swz)
    const int koff = ks * 32 + c * 8;
    pA0[jj] = A + (size_t)(tm + hr) * 4096 + kbase + koff;
    pA1[jj] = A + (size_t)(tm + 128 + hr) * 4096 + kbase + koff;
    pB0[jj] = Bw + (size_t)(tn + hr) * 4096 + kbase + koff;
    pB1[jj] = Bw + (size_t)(tn + 128 + hr) * 4096 + kbase + koff;
    dstq[jj] = q * 1024;                      // wave-uniform LDS byte base
  }

#define STG(P, R) do { \
    gld_lds16(P[0], smem + (R) + dstq[0]); \
    gld_lds16(P[1], smem + (R) + dstq[1]); } while (0)
#define ADV() do { _Pragma("unroll") for (int jj = 0; jj < 2; ++jj) { \
    pA0[jj] += 64; pA1[jj] += 64; pB0[jj] += 64; pB1[jj] += 64; } } while (0)

  // fragment read bases (swizzled read, conflict-free — R3/R5-proven)
  const int wr = w >> 2, wc = w & 3;          // 2M x 4N waves
  const int xl = ((l & 15) >> 1) & 3;
  const int aRd = (wr * 64 + (l & 15)) * 64 + (((l >> 4) ^ xl) * 16);
  const int bRd = (wc * 32 + (l & 15)) * 64 + (((l >> 4) ^ xl) * 16);

  f32x4 acc[8][4];
  const f32x4 zero = {0.f, 0.f, 0.f, 0.f};
#pragma unroll
  for (int m = 0; m < 8; ++m)
#pragma unroll
    for (int n = 0; n < 4; ++n) acc[m][n] = zero;
  short8 fA0[4][2], fA1[4][2], bF[2][2];

#define LDA(DST, BB, MH) do { _Pragma("unroll") for (int mp = 0; mp < 4; ++mp) { \
    _Pragma("unroll") for (int ks = 0; ks < 2; ++ks) \
      DST[mp][ks] = *(const short8*)(smem + (BB) + (MH)*16384 + ks*8192 + mp*1024 + aRd); } } while (0)
#define LDB(BB, NH) do { _Pragma("unroll") for (int np = 0; np < 2; ++np) { \
    _Pragma("unroll") for (int ks = 0; ks < 2; ++ks) \
      bF[np][ks] = *(const short8*)(smem + (BB) + 32768 + (NH)*16384 + ks*8192 + np*1024 + bRd); } } while (0)
#define QUAD(MH, NH, FA) do { _Pragma("unroll") for (int mp = 0; mp < 4; ++mp) { \
    _Pragma("unroll") for (int np = 0; np < 2; ++np) { \
      _Pragma("unroll") for (int ks = 0; ks < 2; ++ks) \
        acc[(MH)*4+mp][(NH)*2+np] = __builtin_amdgcn_mfma_f32_16x16x32_bf16( \
            FA[mp][ks], bF[np][ks], acc[(MH)*4+mp][(NH)*2+np], 0, 0, 0); } } } while (0)
#define BARRF do { __builtin_amdgcn_s_barrier(); asm volatile("" ::: "memory"); } while (0)
#define PRIO1 __builtin_amdgcn_s_setprio(1)
#define PRIO0 __builtin_amdgcn_s_setprio(0)

  // prologue: KT0 -> buf0, KT1 -> buf1; wait KT0; barrier. ptr -> KT2.
  STG(pA0, RA0); STG(pA1, RA1); STG(pB0, RB0); STG(pB1, RB1);
  ADV();
  STG(pA0, BUF1 + RA0); STG(pA1, BUF1 + RA1); STG(pB0, BUF1 + RB0); STG(pB1, BUF1 + RB1);
  ADV();
  asm volatile("s_waitcnt vmcnt(8)" ::: "memory");
  BARRF;

  const int nit = 16;                          // 32 K-tiles per k-half
  for (int t = 0; t < nit; ++t) {
    const bool more = (t + 1 < nit);
#pragma unroll
    for (int h = 0; h < 2; ++h) {
      const int bb = h * BUF1;
      // one K-tile: reads + MFMAs in one fence-free region (compiler
      // emits counted lgkmcnt; reads overlap MFMA issue)
      LDA(fA0, bb, 0);
      LDB(bb, 0);
      LDA(fA1, bb, 1);
      PRIO1; QUAD(0, 0, fA0); PRIO0;
      PRIO1; QUAD(1, 0, fA1); PRIO0;
      LDB(bb, 1);
      PRIO1; QUAD(0, 1, fA0); PRIO0;
      PRIO1; QUAD(1, 1, fA1); PRIO0;
      // read-done boundary (rule-18 hardened): all LDS reads complete
      // before the barrier, so restaging this buffer is WAR-safe.
      asm volatile("s_waitcnt lgkmcnt(0)" ::: "memory");
      __builtin_amdgcn_sched_barrier(0);
      BARRF;
      if (more) {
        STG(pA0, bb + RA0); STG(pA1, bb + RA1);
        STG(pB0, bb + RB0); STG(pB1, bb + RB1);
        ADV();
        asm volatile("s_waitcnt vmcnt(8)" ::: "memory");  // prev KT landed
      } else {
        asm volatile("s_waitcnt vmcnt(0)" ::: "memory");
      }
      if (more || h == 0) BARRF;               // other buffer now valid
    }
  }

  // epilogue: out += acc (+ bias once) via f32 atomics
  const float bmul = (kh == 0) ? 1.0f : 0.0f;
  float bv[4];
#pragma unroll
  for (int n = 0; n < 4; ++n)
    bv[n] = bmul * bias[tn + (n >> 1) * 128 + wc * 32 + (n & 1) * 16 + (l & 15)];
#pragma unroll
  for (int m = 0; m < 8; ++m) {
    const int row = tm + (m >> 2) * 128 + wr * 64 + (m & 3) * 16 + (l >> 4) * 4;
#pragma unroll
    for (int n = 0; n < 4; ++n) {
      const int col = tn + (n >> 1) * 128 + wc * 32 + (n & 1) * 16 + (l & 15);
      float* po = outp + (size_t)row * EMBED + col;
#pragma unroll
      for (int ri = 0; ri < 4; ++ri)
        atomicAdd(po + (size_t)ri * EMBED, acc[m][n][ri] + bv[n]);
    }
  }
}

// ---- launch -------------------------------------------------------------

extern "C" void kernel_launch(void* const* d_in, const int* in_sizes, int n_in,
                              void* d_out, int out_size, void* d_ws, size_t ws_size,
                              hipStream_t stream) {
  const float* xg[3] = {(const float*)d_in[0], (const float*)d_in[3], (const float*)d_in[6]};
  const float* mg[3] = {(const float*)d_in[1], (const float*)d_in[4], (const float*)d_in[7]};
  const float* tg[3] = {(const float*)d_in[2], (const float*)d_in[5], (const float*)d_in[8]};
  const int* idxg[3] = {(const int*)d_in[9], (const int*)d_in[10], (const int*)d_in[11]};
  const float* W_lin = (const float*)d_in[12];
  const float* b_lin = (const float*)d_in[13];
  const float* W_res = (const float*)d_in[14];
  const float* b_res = (const float*)d_in[15];
  const float* W_out = (const float*)d_in[16];
  const float* b_out = (const float*)d_in[17];
  float* out = (float*)d_out;

  char* ws = (char*)d_ws;
  size_t off = 0;
  auto alloc = [&](size_t b) -> char* {
    size_t o = (off + 255) & ~(size_t)255;
    off = o + b;
    return ws + o;
  };

  ushort_t* hidden = (ushort_t*)alloc((size_t)MROWS * INTER * 2);   // 201 MB
  const int Ps[3] = {16, 32, 64};
  const int Kp[3] = {64, 96, 192};
  ushort_t* xsw[3];
  ushort_t* wcat[3];
  for (int g = 0; g < 3; ++g) xsw[g]  = (ushort_t*)alloc((size_t)8192 * Kp[g] * 2);
  for (int g = 0; g < 3; ++g) wcat[g] = (ushort_t*)alloc((size_t)NCAT * Kp[g] * 2);
  ushort_t* wout = (ushort_t*)alloc((size_t)EMBED * INTER * 2);     // 8 MB
  float* bcat = (float*)alloc((size_t)NCAT * 4);

  prep_bcat<<<(NCAT + 255) / 256, 256, 0, stream>>>(b_lin, b_res, bcat);
  prep_wout<<<(EMBED * INTER) / 256, 256, 0, stream>>>(W_out, wout);
  for (int g = 0; g < 3; ++g) {
    int tw = NCAT * Kp[g];
    prep_wcat<<<(tw + 255) / 256, 256, 0, stream>>>(W_lin, W_res, wcat[g], 3 * Ps[g], Kp[g]);
    int tx = 8192 * Kp[g];
    prep_xs<<<(tx + 255) / 256, 256, 0, stream>>>(xg[g], mg[g], tg[g], xsw[g], Ps[g], Kp[g]);
  }
  // phase 1: per group, [8192 x Kp] @ [5120 x Kp]^T
  for (int g = 0; g < 3; ++g)
    gemm128p1<<<dim3(64, 40), 256, 0, stream>>>(xsw[g], wcat[g], Kp[g], bcat,
                                                hidden, out, idxg[g]);
  // phase 2: [24576 x 4096] @ [1024 x 4096]^T, K-split=2, out += acc (+b_out)
  gemm256k<<<dim3(768), 512, 0, stream>>>(hidden, wout, b_out, out);
}

// Round 7
// 418.498 us; speedup vs baseline: 1.2176x; 1.2176x over previous
//
#include <hip/hip_runtime.h>
#include <hip/hip_bf16.h>
#include <math.h>

typedef unsigned short ushort_t;
typedef short short8 __attribute__((ext_vector_type(8)));
typedef float f32x4 __attribute__((ext_vector_type(4)));

#define N_TOK 512
#define EMBED 1024
#define INTER 4096
#define NCAT  5120   /* INTER + EMBED */
#define MROWS 24576  /* 48 * 512 */

__device__ __forceinline__ ushort_t f2bf(float f) {
  union { float f; unsigned int u; } c; c.f = f;
  unsigned int u = c.u;
  unsigned int r = u + 0x7fffu + ((u >> 16) & 1u);
  return (ushort_t)(r >> 16);
}

__device__ __forceinline__ void gld_lds16(const void* g, void* l) {
  __builtin_amdgcn_global_load_lds(
      (const __attribute__((address_space(1))) void*)g,
      (__attribute__((address_space(3))) void*)l, 16, 0, 0);
}

// ---- prep kernels -------------------------------------------------------

__global__ void prep_bcat(const float* __restrict__ bl, const float* __restrict__ br,
                          float* __restrict__ dst) {
  int i = blockIdx.x * 256 + threadIdx.x;
  if (i >= NCAT) return;
  dst[i] = (i < INTER) ? bl[i] : br[i - INTER];
}

__global__ void prep_wout(const float* __restrict__ W, ushort_t* __restrict__ dst) {
  int i = blockIdx.x * 256 + threadIdx.x;   // total EMBED*INTER, exact grid
  dst[i] = f2bf(W[i]);
}

__global__ void prep_wcat(const float* __restrict__ Wl, const float* __restrict__ Wr,
                          ushort_t* __restrict__ dst, int P3, int Kpad) {
  int i = blockIdx.x * 256 + threadIdx.x;
  int total = NCAT * Kpad;
  if (i >= total) return;
  int r = i / Kpad, j = i - r * Kpad;
  float v = 0.f;
  if (j < P3) {
    float scale = 96.0f / (float)P3;
    float src = (j + 0.5f) * scale - 0.5f;
    src = fminf(fmaxf(src, 0.0f), 95.0f);
    int i0 = (int)src;
    int i1 = min(i0 + 1, 95);
    float tt = src - (float)i0;
    const float* Wrow = (r < INTER) ? (Wl + (size_t)r * 96)
                                    : (Wr + (size_t)(r - INTER) * 96);
    v = Wrow[i0] * (1.f - tt) + Wrow[i1] * tt;
  }
  dst[i] = f2bf(v);
}

__global__ void prep_xs(const float* __restrict__ x, const float* __restrict__ m,
                        const float* __restrict__ t, ushort_t* __restrict__ dst,
                        int p, int Kpad) {
  int i = blockIdx.x * 256 + threadIdx.x;
  int total = 8192 * Kpad;
  if (i >= total) return;
  int r = i / Kpad, j = i - r * Kpad;
  float v = 0.f;
  int p3 = 3 * p;
  if (j < p3) {
    size_t base = (size_t)r * p;
    if (j < p)           v = x[base + j];
    else if (j < 2 * p)  v = m[base + j - p];
    else                 v = t[base + j - 2 * p];
  }
  dst[i] = f2bf(v);
}

// ---- phase-1: 128x128 GEMM (R3 structure, proven) -----------------------
__global__ __launch_bounds__(256)
void gemm128p1(const ushort_t* __restrict__ A, const ushort_t* __restrict__ B,
               int Kpad, const float* __restrict__ bias,
               ushort_t* __restrict__ hidden, float* __restrict__ outp,
               const int* __restrict__ idxg) {
  __shared__ __align__(16) ushort_t lA[2][128 * 32];
  __shared__ __align__(16) ushort_t lB[2][128 * 32];
  const int t = threadIdx.x;
  const int wave = t >> 6, lane = t & 63;
  const int tm = blockIdx.x * 128, tn = blockIdx.y * 128;

  const int chunk = wave * 2;
  const int srow = chunk * 16 + (lane >> 2);
  const int scol = (((lane & 3) ^ ((lane >> 3) & 3)) * 8);
  const ushort_t* gA0 = A + (size_t)(tm + srow) * Kpad + scol;
  const ushort_t* gA1 = gA0 + (size_t)16 * Kpad;
  const ushort_t* gB0 = B + (size_t)(tn + srow) * Kpad + scol;
  const ushort_t* gB1 = gB0 + (size_t)16 * Kpad;
  const int ldsOff0 = chunk * 512;
  const int ldsOff1 = ldsOff0 + 512;

  const int wr = wave >> 1, wc = wave & 1;
  const f32x4 zero = {0.f, 0.f, 0.f, 0.f};
  f32x4 acc[4][4];
#pragma unroll
  for (int m2 = 0; m2 < 4; ++m2)
#pragma unroll
    for (int n2 = 0; n2 < 4; ++n2) acc[m2][n2] = zero;

  const int xf = ((lane & 15) >> 1) & 3;
  const int fcol = (((lane >> 4) ^ xf)) * 8;
  const int aoff = (wr * 64 + (lane & 15)) * 32 + fcol;
  const int boff = (wc * 64 + (lane & 15)) * 32 + fcol;

  const int nk = Kpad >> 5;
  gld_lds16(gA0, &lA[0][ldsOff0]); gld_lds16(gA1, &lA[0][ldsOff1]);
  gld_lds16(gB0, &lB[0][ldsOff0]); gld_lds16(gB1, &lB[0][ldsOff1]);
  gA0 += 32; gA1 += 32; gB0 += 32; gB1 += 32;

  for (int kk = 0; kk < nk; ++kk) {
    const int cur = kk & 1;
    if (kk + 1 < nk) {
      const int nxt = cur ^ 1;
      gld_lds16(gA0, &lA[nxt][ldsOff0]); gld_lds16(gA1, &lA[nxt][ldsOff1]);
      gld_lds16(gB0, &lB[nxt][ldsOff0]); gld_lds16(gB1, &lB[nxt][ldsOff1]);
      gA0 += 32; gA1 += 32; gB0 += 32; gB1 += 32;
      asm volatile("s_waitcnt vmcnt(4)" ::: "memory");
    } else {
      asm volatile("s_waitcnt vmcnt(0)" ::: "memory");
    }
    __builtin_amdgcn_s_barrier();
    asm volatile("" ::: "memory");

    const ushort_t* pa = &lA[cur][0] + aoff;
    const ushort_t* pb = &lB[cur][0] + boff;
    short8 aF[4], bF[4];
#pragma unroll
    for (int m2 = 0; m2 < 4; ++m2) aF[m2] = *(const short8*)(pa + m2 * 16 * 32);
#pragma unroll
    for (int n2 = 0; n2 < 4; ++n2) bF[n2] = *(const short8*)(pb + n2 * 16 * 32);
#pragma unroll
    for (int m2 = 0; m2 < 4; ++m2)
#pragma unroll
      for (int n2 = 0; n2 < 4; ++n2)
        acc[m2][n2] = __builtin_amdgcn_mfma_f32_16x16x32_bf16(
            aF[m2], bF[n2], acc[m2][n2], 0, 0, 0);
    __builtin_amdgcn_s_barrier();
    asm volatile("" ::: "memory");
  }

  const int layer = idxg[tm >> 9];
  const int rowBase = layer * N_TOK + (tm & (N_TOK - 1));

#pragma unroll
  for (int m2 = 0; m2 < 4; ++m2) {
#pragma unroll
    for (int n2 = 0; n2 < 4; ++n2) {
      const int colg = tn + wc * 64 + n2 * 16 + (lane & 15);
      const float bv = bias[colg];
#pragma unroll
      for (int r = 0; r < 4; ++r) {
        const int rowl = wr * 64 + m2 * 16 + (lane >> 4) * 4 + r;
        const float v = acc[m2][n2][r];
        const int grow = rowBase + rowl;
        if (colg < INTER) {
          float h = v + bv;
          h = h / (1.f + expf(-h));
          hidden[(size_t)grow * INTER + colg] = f2bf(h);
        } else {
          outp[(size_t)grow * EMBED + (colg - INTER)] = v + bv;
        }
      }
    }
  }
}

// ---- phase-2: 192x256 full-K 8-phase MFMA GEMM (no atomics) ------------
// A = hidden [24576][4096] bf16, B = wout [1024][4096] bf16 (B^T layout).
// Grid 512 = 8 xcd * 16 mtl * 4 nt; full K=4096 per block -> single writer
// per output element: plain out += acc + bias.  2 perfectly balanced
// rounds (512 = 2*256 CUs).
// LDS 112 KB: 2 buf x {A 24 KB [2ks][192r][64B], B 32 KB [2ks][256r][64B]}
// with R3-proven 16B-chunk XOR swizzle (pos = src ^ ((row>>1)&3)).
// Per KT (BK=64) 4 phases, quadrant order Q(ha,nh) = (0,0),(1,0),(0,1),(1,1);
// per phase: {new frag ds_reads, stage slot, barrier, lgkmcnt(0)+sched_bar,
// setprio1, 12 MFMA, setprio0, barrier}  (m201 phase interior, rule-18).
// Ledger (7 loads/KT/thread = A 3 + B 4), steady iter t (KT 2t buf0, 2t+1 buf1):
//   entry in-flight: KT(2t+1).{A3,B4} = 7
//   ph3: stage KT(2t+2).A->buf0 (A free after ph2)
//   ph4: stage KT(2t+2).B->buf0 ; vmcnt(7) drains KT(2t+1) (used ph5+)
//   ph7: stage KT(2t+3).A->buf1
//   ph8: stage KT(2t+3).B->buf1 ; vmcnt(7) drains KT(2t+2) (used next ph1)
#define AREG 24576
#define BREG 32768
#define BUFSZ 57344

__global__ __launch_bounds__(512, 2)
void gemm192(const ushort_t* __restrict__ A, const ushort_t* __restrict__ Bw,
             const float* __restrict__ bias, float* __restrict__ outp) {
  __shared__ __align__(16) char smem[2 * BUFSZ];
  const int tid = threadIdx.x;
  const int w = tid >> 6, l = tid & 63;

  const int L = blockIdx.x;
  const int xcd = L & 7, j = L >> 3;          // j in [0,64)
  const int nt = j & 3;
  const int mt = xcd * 16 + (j >> 2);         // 128 m-tiles
  const int tm = mt * 192, tn = nt * 256;

  // ---- staging (pre-swizzled global source, linear LDS dest) ----
  const ushort_t* pA[3]; int dA[3];
#pragma unroll
  for (int jj = 0; jj < 3; ++jj) {
    const int q = w * 3 + jj;                 // 0..23
    const int ks = q / 12, rb = q % 12;
    const int row = rb * 16 + (l >> 2);
    const int c = (l & 3) ^ ((row >> 1) & 3);
    pA[jj] = A + (size_t)(tm + row) * 4096 + ks * 32 + c * 8;
    dA[jj] = ks * 12288 + rb * 1024;
  }
  const ushort_t* pB[4]; int dB[4];
#pragma unroll
  for (int jj = 0; jj < 4; ++jj) {
    const int q = w * 4 + jj;                 // 0..31
    const int ks = q >> 4, rb = q & 15;
    const int row = rb * 16 + (l >> 2);
    const int c = (l & 3) ^ ((row >> 1) & 3);
    pB[jj] = Bw + (size_t)(tn + row) * 4096 + ks * 32 + c * 8;
    dB[jj] = AREG + ks * 16384 + rb * 1024;
  }

#define STGA(BB, E) do { _Pragma("unroll") for (int jj = 0; jj < 3; ++jj) \
    gld_lds16(pA[jj] + (E), smem + (BB) + dA[jj]); } while (0)
#define STGB(BB, E) do { _Pragma("unroll") for (int jj = 0; jj < 4; ++jj) \
    gld_lds16(pB[jj] + (E), smem + (BB) + dB[jj]); } while (0)
#define ADV() do { _Pragma("unroll") for (int jj = 0; jj < 3; ++jj) pA[jj] += 128; \
    _Pragma("unroll") for (int jj = 0; jj < 4; ++jj) pB[jj] += 128; } while (0)

  // ---- fragment read bases (swizzled read, conflict-free) ----
  const int wr = w >> 2, wc = w & 3;          // 2M x 4N waves; wave tile 96x64
  const int xl = ((l & 15) >> 1) & 3;
  const int cx = ((l >> 4) ^ xl) * 16;
  const int aRd = (wr * 96 + (l & 15)) * 64 + cx;
  const int bRd = AREG + (wc * 64 + (l & 15)) * 64 + cx;

  f32x4 acc[6][4];
  const f32x4 zero = {0.f, 0.f, 0.f, 0.f};
#pragma unroll
  for (int m = 0; m < 6; ++m)
#pragma unroll
    for (int n = 0; n < 4; ++n) acc[m][n] = zero;
  short8 aFa[3][2], aFb[3][2], bF0[2][2], bF1[2][2];

#define LDAA(D, BB, HA) do { _Pragma("unroll") for (int mp = 0; mp < 3; ++mp) { \
    _Pragma("unroll") for (int ks = 0; ks < 2; ++ks) \
      D[mp][ks] = *(const short8*)(smem + (BB) + ks * 12288 + ((HA) * 3 + mp) * 1024 + aRd); } } while (0)
#define LDBB(D, BB, NH) do { _Pragma("unroll") for (int np = 0; np < 2; ++np) { \
    _Pragma("unroll") for (int ks = 0; ks < 2; ++ks) \
      D[np][ks] = *(const short8*)(smem + (BB) + ks * 16384 + (NH) * 2048 + np * 1024 + bRd); } } while (0)
#define QUAD(FA, FB, HA, NH) do { _Pragma("unroll") for (int mp = 0; mp < 3; ++mp) { \
    _Pragma("unroll") for (int np = 0; np < 2; ++np) { \
      _Pragma("unroll") for (int ks = 0; ks < 2; ++ks) \
        acc[(HA)*3+mp][(NH)*2+np] = __builtin_amdgcn_mfma_f32_16x16x32_bf16( \
            FA[mp][ks], FB[np][ks], acc[(HA)*3+mp][(NH)*2+np], 0, 0, 0); } } } while (0)
#define BARR do { __builtin_amdgcn_s_barrier(); asm volatile("" ::: "memory"); } while (0)
#define LGKM0 do { asm volatile("s_waitcnt lgkmcnt(0)" ::: "memory"); \
    __builtin_amdgcn_sched_barrier(0); } while (0)
#define WAITV(N) do { asm volatile("s_waitcnt vmcnt(" #N ")" ::: "memory"); \
    __builtin_amdgcn_sched_barrier(0); } while (0)
#define PRIO1 __builtin_amdgcn_s_setprio(1)
#define PRIO0 __builtin_amdgcn_s_setprio(0)

  // prologue: KT0 -> buf0, KT1 -> buf1; drain KT0; barrier. ptr -> KT2.
  STGA(0, 0); STGB(0, 0);
  STGA(BUFSZ, 64); STGB(BUFSZ, 64);
  ADV();
  WAITV(7);
  BARR;

  const int nit = 32;                          // 64 K-tiles
  for (int t = 0; t < nit; ++t) {
    const bool more = (t + 1 < nit);
    // ---- KT(2t) on buf0 ----
    // ph1: Q(0,0)
    LDAA(aFa, 0, 0);
    LDBB(bF0, 0, 0);
    BARR; LGKM0; PRIO1; QUAD(aFa, bF0, 0, 0); PRIO0; BARR;
    // ph2: Q(1,0)
    LDAA(aFb, 0, 1);
    BARR; LGKM0; PRIO1; QUAD(aFb, bF0, 1, 0); PRIO0; BARR;
    // ph3: Q(0,1)   (buf0.A fully read -> restage)
    LDBB(bF1, 0, 1);
    if (more) STGA(0, 0);                      // KT(2t+2).A
    BARR; LGKM0; PRIO1; QUAD(aFa, bF1, 0, 1); PRIO0; BARR;
    // ph4: Q(1,1)   (buf0.B fully read -> restage)
    if (more) { STGB(0, 0); WAITV(7); }        // KT(2t+2).B; drain KT(2t+1)
    else      { WAITV(0); }
    BARR; PRIO1; QUAD(aFb, bF1, 1, 1); PRIO0; BARR;
    // ---- KT(2t+1) on buf1 ----
    // ph5: Q(0,0)
    LDAA(aFa, BUFSZ, 0);
    LDBB(bF0, BUFSZ, 0);
    BARR; LGKM0; PRIO1; QUAD(aFa, bF0, 0, 0); PRIO0; BARR;
    // ph6: Q(1,0)
    LDAA(aFb, BUFSZ, 1);
    BARR; LGKM0; PRIO1; QUAD(aFb, bF0, 1, 0); PRIO0; BARR;
    // ph7: Q(0,1)
    LDBB(bF1, BUFSZ, 1);
    if (more) STGA(BUFSZ, 64);                 // KT(2t+3).A
    BARR; LGKM0; PRIO1; QUAD(aFa, bF1, 0, 1); PRIO0; BARR;
    // ph8: Q(1,1)
    if (more) { STGB(BUFSZ, 64); WAITV(7); }   // KT(2t+3).B; drain KT(2t+2)
    BARR; PRIO1; QUAD(aFb, bF1, 1, 1); PRIO0; BARR;
    if (more) ADV();
  }

  // ---- epilogue: out += acc + bias (single writer, no atomics) ----
  float bv[4];
#pragma unroll
  for (int n = 0; n < 4; ++n)
    bv[n] = bias[tn + wc * 64 + (n >> 1) * 32 + (n & 1) * 16 + (l & 15)];
#pragma unroll
  for (int m = 0; m < 6; ++m) {
    const int row = tm + wr * 96 + m * 16 + (l >> 4) * 4;
#pragma unroll
    for (int n = 0; n < 4; ++n) {
      const int col = tn + wc * 64 + (n >> 1) * 32 + (n & 1) * 16 + (l & 15);
      float* po = outp + (size_t)row * EMBED + col;
#pragma unroll
      for (int ri = 0; ri < 4; ++ri)
        po[(size_t)ri * EMBED] += acc[m][n][ri] + bv[n];
    }
  }
}

// ---- launch -------------------------------------------------------------

extern "C" void kernel_launch(void* const* d_in, const int* in_sizes, int n_in,
                              void* d_out, int out_size, void* d_ws, size_t ws_size,
                              hipStream_t stream) {
  const float* xg[3] = {(const float*)d_in[0], (const float*)d_in[3], (const float*)d_in[6]};
  const float* mg[3] = {(const float*)d_in[1], (const float*)d_in[4], (const float*)d_in[7]};
  const float* tg[3] = {(const float*)d_in[2], (const float*)d_in[5], (const float*)d_in[8]};
  const int* idxg[3] = {(const int*)d_in[9], (const int*)d_in[10], (const int*)d_in[11]};
  const float* W_lin = (const float*)d_in[12];
  const float* b_lin = (const float*)d_in[13];
  const float* W_res = (const float*)d_in[14];
  const float* b_res = (const float*)d_in[15];
  const float* W_out = (const float*)d_in[16];
  const float* b_out = (const float*)d_in[17];
  float* out = (float*)d_out;

  char* ws = (char*)d_ws;
  size_t off = 0;
  auto alloc = [&](size_t b) -> char* {
    size_t o = (off + 255) & ~(size_t)255;
    off = o + b;
    return ws + o;
  };

  ushort_t* hidden = (ushort_t*)alloc((size_t)MROWS * INTER * 2);   // 201 MB
  const int Ps[3] = {16, 32, 64};
  const int Kp[3] = {64, 96, 192};
  ushort_t* xsw[3];
  ushort_t* wcat[3];
  for (int g = 0; g < 3; ++g) xsw[g]  = (ushort_t*)alloc((size_t)8192 * Kp[g] * 2);
  for (int g = 0; g < 3; ++g) wcat[g] = (ushort_t*)alloc((size_t)NCAT * Kp[g] * 2);
  ushort_t* wout = (ushort_t*)alloc((size_t)EMBED * INTER * 2);     // 8 MB
  float* bcat = (float*)alloc((size_t)NCAT * 4);

  prep_bcat<<<(NCAT + 255) / 256, 256, 0, stream>>>(b_lin, b_res, bcat);
  prep_wout<<<(EMBED * INTER) / 256, 256, 0, stream>>>(W_out, wout);
  for (int g = 0; g < 3; ++g) {
    int tw = NCAT * Kp[g];
    prep_wcat<<<(tw + 255) / 256, 256, 0, stream>>>(W_lin, W_res, wcat[g], 3 * Ps[g], Kp[g]);
    int tx = 8192 * Kp[g];
    prep_xs<<<(tx + 255) / 256, 256, 0, stream>>>(xg[g], mg[g], tg[g], xsw[g], Ps[g], Kp[g]);
  }
  // phase 1: per group, [8192 x Kp] @ [5120 x Kp]^T
  for (int g = 0; g < 3; ++g)
    gemm128p1<<<dim3(64, 40), 256, 0, stream>>>(xsw[g], wcat[g], Kp[g], bcat,
                                                hidden, out, idxg[g]);
  // phase 2: [24576 x 4096] @ [1024 x 4096]^T, full K, out += acc + b_out
  gemm192<<<dim3(512), 512, 0, stream>>>(hidden, wout, b_out, out);
}

// Round 8
// 405.980 us; speedup vs baseline: 1.2551x; 1.0308x over previous
//
#include <hip/hip_runtime.h>
#include <hip/hip_bf16.h>
#include <math.h>

typedef unsigned short ushort_t;
typedef short short8 __attribute__((ext_vector_type(8)));
typedef float f32x4 __attribute__((ext_vector_type(4)));

#define N_TOK 512
#define EMBED 1024
#define INTER 4096
#define NCAT  5120   /* INTER + EMBED */
#define MROWS 24576  /* 48 * 512 */

__device__ __forceinline__ ushort_t f2bf(float f) {
  union { float f; unsigned int u; } c; c.f = f;
  unsigned int u = c.u;
  unsigned int r = u + 0x7fffu + ((u >> 16) & 1u);
  return (ushort_t)(r >> 16);
}

__device__ __forceinline__ void gld_lds16(const void* g, void* l) {
  __builtin_amdgcn_global_load_lds(
      (const __attribute__((address_space(1))) void*)g,
      (__attribute__((address_space(3))) void*)l, 16, 0, 0);
}

// ---- prep kernels -------------------------------------------------------

__global__ void prep_bcat(const float* __restrict__ bl, const float* __restrict__ br,
                          float* __restrict__ dst) {
  int i = blockIdx.x * 256 + threadIdx.x;
  if (i >= NCAT) return;
  dst[i] = (i < INTER) ? bl[i] : br[i - INTER];
}

__global__ void prep_wout(const float* __restrict__ W, ushort_t* __restrict__ dst) {
  int i = blockIdx.x * 256 + threadIdx.x;   // total EMBED*INTER, exact grid
  dst[i] = f2bf(W[i]);
}

__global__ void prep_wcat(const float* __restrict__ Wl, const float* __restrict__ Wr,
                          ushort_t* __restrict__ dst, int P3, int Kpad) {
  int i = blockIdx.x * 256 + threadIdx.x;
  int total = NCAT * Kpad;
  if (i >= total) return;
  int r = i / Kpad, j = i - r * Kpad;
  float v = 0.f;
  if (j < P3) {
    float scale = 96.0f / (float)P3;
    float src = (j + 0.5f) * scale - 0.5f;
    src = fminf(fmaxf(src, 0.0f), 95.0f);
    int i0 = (int)src;
    int i1 = min(i0 + 1, 95);
    float tt = src - (float)i0;
    const float* Wrow = (r < INTER) ? (Wl + (size_t)r * 96)
                                    : (Wr + (size_t)(r - INTER) * 96);
    v = Wrow[i0] * (1.f - tt) + Wrow[i1] * tt;
  }
  dst[i] = f2bf(v);
}

__global__ void prep_xs(const float* __restrict__ x, const float* __restrict__ m,
                        const float* __restrict__ t, ushort_t* __restrict__ dst,
                        int p, int Kpad) {
  int i = blockIdx.x * 256 + threadIdx.x;
  int total = 8192 * Kpad;
  if (i >= total) return;
  int r = i / Kpad, j = i - r * Kpad;
  float v = 0.f;
  int p3 = 3 * p;
  if (j < p3) {
    size_t base = (size_t)r * p;
    if (j < p)           v = x[base + j];
    else if (j < 2 * p)  v = m[base + j - p];
    else                 v = t[base + j - 2 * p];
  }
  dst[i] = f2bf(v);
}

// ---- phase-1: merged 3-group 128x128 GEMM (R3/R7 interior, proven) ------
__global__ __launch_bounds__(256)
void gemm128p1g(const ushort_t* __restrict__ A0, const ushort_t* __restrict__ A1,
                const ushort_t* __restrict__ A2,
                const ushort_t* __restrict__ B0w, const ushort_t* __restrict__ B1w,
                const ushort_t* __restrict__ B2w,
                const float* __restrict__ bias,
                ushort_t* __restrict__ hidden, float* __restrict__ outp,
                const int* __restrict__ i0, const int* __restrict__ i1,
                const int* __restrict__ i2) {
  __shared__ __align__(16) ushort_t lA[2][128 * 32];
  __shared__ __align__(16) ushort_t lB[2][128 * 32];
  const int t = threadIdx.x;
  const int wave = t >> 6, lane = t & 63;
  const int gm = blockIdx.x >> 6;             // group 0/1/2
  const int tm = (blockIdx.x & 63) * 128;     // within-group row tile
  const int tn = blockIdx.y * 128;
  const ushort_t* A = (gm == 0) ? A0 : (gm == 1) ? A1 : A2;
  const ushort_t* B = (gm == 0) ? B0w : (gm == 1) ? B1w : B2w;
  const int* idxg   = (gm == 0) ? i0 : (gm == 1) ? i1 : i2;
  const int Kpad    = (gm == 0) ? 64 : (gm == 1) ? 96 : 192;

  const int chunk = wave * 2;
  const int srow = chunk * 16 + (lane >> 2);
  const int scol = (((lane & 3) ^ ((lane >> 3) & 3)) * 8);
  const ushort_t* gA0 = A + (size_t)(tm + srow) * Kpad + scol;
  const ushort_t* gA1 = gA0 + (size_t)16 * Kpad;
  const ushort_t* gB0 = B + (size_t)(tn + srow) * Kpad + scol;
  const ushort_t* gB1 = gB0 + (size_t)16 * Kpad;
  const int ldsOff0 = chunk * 512;
  const int ldsOff1 = ldsOff0 + 512;

  const int wr = wave >> 1, wc = wave & 1;
  const f32x4 zero = {0.f, 0.f, 0.f, 0.f};
  f32x4 acc[4][4];
#pragma unroll
  for (int m2 = 0; m2 < 4; ++m2)
#pragma unroll
    for (int n2 = 0; n2 < 4; ++n2) acc[m2][n2] = zero;

  const int xf = ((lane & 15) >> 1) & 3;
  const int fcol = (((lane >> 4) ^ xf)) * 8;
  const int aoff = (wr * 64 + (lane & 15)) * 32 + fcol;
  const int boff = (wc * 64 + (lane & 15)) * 32 + fcol;

  const int nk = Kpad >> 5;
  gld_lds16(gA0, &lA[0][ldsOff0]); gld_lds16(gA1, &lA[0][ldsOff1]);
  gld_lds16(gB0, &lB[0][ldsOff0]); gld_lds16(gB1, &lB[0][ldsOff1]);
  gA0 += 32; gA1 += 32; gB0 += 32; gB1 += 32;

  for (int kk = 0; kk < nk; ++kk) {
    const int cur = kk & 1;
    if (kk + 1 < nk) {
      const int nxt = cur ^ 1;
      gld_lds16(gA0, &lA[nxt][ldsOff0]); gld_lds16(gA1, &lA[nxt][ldsOff1]);
      gld_lds16(gB0, &lB[nxt][ldsOff0]); gld_lds16(gB1, &lB[nxt][ldsOff1]);
      gA0 += 32; gA1 += 32; gB0 += 32; gB1 += 32;
      asm volatile("s_waitcnt vmcnt(4)" ::: "memory");
    } else {
      asm volatile("s_waitcnt vmcnt(0)" ::: "memory");
    }
    __builtin_amdgcn_s_barrier();
    asm volatile("" ::: "memory");

    const ushort_t* pa = &lA[cur][0] + aoff;
    const ushort_t* pb = &lB[cur][0] + boff;
    short8 aF[4], bF[4];
#pragma unroll
    for (int m2 = 0; m2 < 4; ++m2) aF[m2] = *(const short8*)(pa + m2 * 16 * 32);
#pragma unroll
    for (int n2 = 0; n2 < 4; ++n2) bF[n2] = *(const short8*)(pb + n2 * 16 * 32);
#pragma unroll
    for (int m2 = 0; m2 < 4; ++m2)
#pragma unroll
      for (int n2 = 0; n2 < 4; ++n2)
        acc[m2][n2] = __builtin_amdgcn_mfma_f32_16x16x32_bf16(
            aF[m2], bF[n2], acc[m2][n2], 0, 0, 0);
    __builtin_amdgcn_s_barrier();
    asm volatile("" ::: "memory");
  }

  const int layer = idxg[tm >> 9];
  const int rowBase = layer * N_TOK + (tm & (N_TOK - 1));

#pragma unroll
  for (int m2 = 0; m2 < 4; ++m2) {
#pragma unroll
    for (int n2 = 0; n2 < 4; ++n2) {
      const int colg = tn + wc * 64 + n2 * 16 + (lane & 15);
      const float bv = bias[colg];
#pragma unroll
      for (int r = 0; r < 4; ++r) {
        const int rowl = wr * 64 + m2 * 16 + (lane >> 4) * 4 + r;
        const float v = acc[m2][n2][r];
        const int grow = rowBase + rowl;
        if (colg < INTER) {
          float h = v + bv;
          h = h / (1.f + expf(-h));
          hidden[(size_t)grow * INTER + colg] = f2bf(h);
        } else {
          outp[(size_t)grow * EMBED + (colg - INTER)] = v + bv;
        }
      }
    }
  }
}

// ---- phase-2: 192x128 full-K GEMM, 2 blocks/CU co-resident -------------
// A = hidden [24576][4096] bf16, B = wout [1024][4096] bf16 (B^T layout).
// Grid 1024 = 8 xcd * 16 mtl * 8 nt (nt fastest -> concurrent A-reuse).
// LDS 2 x 40960 = 81920 B/block -> exactly 2 blocks/CU (163840 = 160 KiB).
// 512 thr, 8 waves 4Mx2N, wave tile 48x64, acc 12 f32x4.
// Buffer layout per buf: A [2ks][192r][64B] @0, B [2ks][128r][64B] @24576,
// 16B-chunk XOR swizzle (pos = src ^ ((row>>1)&3)) - R3-proven, 0 conflicts.
// 2 phases per KT (nh=0/1): {reads, stage slot, BARR, lgkm0, 12 MFMA, BARR}.
// Stage ledger (5 loads/KT/thread = A3 + B2), KT t in buf t&1:
//   ph1: stage B(t+1) -> buf^1  (B-region free since KT(t-1).ph2 close)
//   ph2: stage A(t+2) -> buf    (A-region free since ph1 close)
//   ph2-end: vmcnt(3) leaves A(t+2) in flight, drains A(t+1)+B(t+1)
#define P2BUF 40960
#define P2BOFF 24576

__global__ __launch_bounds__(512, 4)
void gemm192n128(const ushort_t* __restrict__ A, const ushort_t* __restrict__ Bw,
                 const float* __restrict__ bias, float* __restrict__ outp) {
  __shared__ __align__(16) char smem[2 * P2BUF];
  const int tid = threadIdx.x;
  const int w = tid >> 6, l = tid & 63;

  const int L = blockIdx.x;
  const int xcd = L & 7, j = L >> 3;          // j in [0,128)
  const int nt = j & 7, mtl = j >> 3;         // nt fastest: A-slab reuse
  const int tm = (xcd * 16 + mtl) * 192, tn = nt * 128;

  // staging source pointers (pre-swizzled global, linear LDS dest)
  const ushort_t* pA[3]; int dA[3];
#pragma unroll
  for (int jj = 0; jj < 3; ++jj) {
    const int q = w * 3 + jj;                 // 0..23
    const int ks = q / 12, rb = q % 12;
    const int row = rb * 16 + (l >> 2);
    const int c = (l & 3) ^ ((row >> 1) & 3);
    pA[jj] = A + (size_t)(tm + row) * 4096 + ks * 32 + c * 8;
    dA[jj] = ks * 12288 + rb * 1024;
  }
  const ushort_t* pB[2]; int dB[2];
#pragma unroll
  for (int jj = 0; jj < 2; ++jj) {
    const int q = w * 2 + jj;                 // 0..15
    const int ks = q >> 3, rb = q & 7;
    const int row = rb * 16 + (l >> 2);
    const int c = (l & 3) ^ ((row >> 1) & 3);
    pB[jj] = Bw + (size_t)(tn + row) * 4096 + ks * 32 + c * 8;
    dB[jj] = P2BOFF + ks * 8192 + rb * 1024;
  }

#define STGA3(BB) do { _Pragma("unroll") for (int jj = 0; jj < 3; ++jj) \
    gld_lds16(pA[jj], smem + (BB) + dA[jj]); \
    _Pragma("unroll") for (int jj = 0; jj < 3; ++jj) pA[jj] += 64; } while (0)
#define STGB2(BB) do { _Pragma("unroll") for (int jj = 0; jj < 2; ++jj) \
    gld_lds16(pB[jj], smem + (BB) + dB[jj]); \
    _Pragma("unroll") for (int jj = 0; jj < 2; ++jj) pB[jj] += 64; } while (0)

  // fragment read bases (swizzled read, conflict-free)
  const int wr = w >> 1, wc = w & 1;          // 4M x 2N
  const int xl = ((l & 15) >> 1) & 3;
  const int cx = ((l >> 4) ^ xl) * 16;
  const int aBase = (wr * 48 + (l & 15)) * 64 + cx;
  const int bBase = P2BOFF + (wc * 64 + (l & 15)) * 64 + cx;

  f32x4 acc[3][4];
  const f32x4 zero = {0.f, 0.f, 0.f, 0.f};
#pragma unroll
  for (int m = 0; m < 3; ++m)
#pragma unroll
    for (int n = 0; n < 4; ++n) acc[m][n] = zero;
  short8 aF[3][2], bF[2][2];

#define LDA6(BB) do { _Pragma("unroll") for (int mp = 0; mp < 3; ++mp) { \
    _Pragma("unroll") for (int ks = 0; ks < 2; ++ks) \
      aF[mp][ks] = *(const short8*)(smem + (BB) + ks * 12288 + mp * 1024 + aBase); } } while (0)
#define LDB4(BB, NH) do { _Pragma("unroll") for (int np = 0; np < 2; ++np) { \
    _Pragma("unroll") for (int ks = 0; ks < 2; ++ks) \
      bF[np][ks] = *(const short8*)(smem + (BB) + ks * 8192 + (NH) * 2048 + np * 1024 + bBase); } } while (0)
#define QUAD12(NH) do { _Pragma("unroll") for (int mp = 0; mp < 3; ++mp) { \
    _Pragma("unroll") for (int np = 0; np < 2; ++np) { \
      _Pragma("unroll") for (int ks = 0; ks < 2; ++ks) \
        acc[mp][(NH)*2+np] = __builtin_amdgcn_mfma_f32_16x16x32_bf16( \
            aF[mp][ks], bF[np][ks], acc[mp][(NH)*2+np], 0, 0, 0); } } } while (0)
#define BARR do { __builtin_amdgcn_s_barrier(); asm volatile("" ::: "memory"); } while (0)
#define LGKM0 do { asm volatile("s_waitcnt lgkmcnt(0)" ::: "memory"); \
    __builtin_amdgcn_sched_barrier(0); } while (0)
#define WAITV(N) do { asm volatile("s_waitcnt vmcnt(" #N ")" ::: "memory"); \
    __builtin_amdgcn_sched_barrier(0); } while (0)
#define PRIO1 __builtin_amdgcn_s_setprio(1)
#define PRIO0 __builtin_amdgcn_s_setprio(0)

  // prologue: A0,B0 -> buf0; A1 -> buf1; drain KT0 (leave A1 in flight)
  STGA3(0); STGB2(0);
  STGA3(P2BUF);
  WAITV(3);
  BARR;

  const int nit2 = 32;                         // 64 KTs, 2 per iteration
  for (int t2 = 0; t2 < nit2; ++t2) {
    const bool morA = (t2 + 1 < nit2);         // A(t+2) exists
    // ---- KT even (buf0) ----
    LDA6(0); LDB4(0, 0);
    STGB2(P2BUF);                              // B(t+1) -> buf1 (always valid)
    BARR; LGKM0; PRIO1; QUAD12(0); PRIO0; BARR;
    LDB4(0, 1);
    if (morA) STGA3(0);                        // A(t+2) -> buf0
    BARR; LGKM0; PRIO1; QUAD12(1); PRIO0;
    if (morA) { WAITV(3); } else { WAITV(0); } // drain A(t+1)+B(t+1)
    BARR;
    // ---- KT odd (buf1) ----
    LDA6(P2BUF); LDB4(P2BUF, 0);
    if (morA) STGB2(0);                        // B(t+2) -> buf0
    BARR; LGKM0; PRIO1; QUAD12(0); PRIO0; BARR;
    LDB4(P2BUF, 1);
    if (morA) STGA3(P2BUF);                    // A(t+3) -> buf1
    BARR; LGKM0; PRIO1; QUAD12(1); PRIO0;
    if (morA) { WAITV(3); } else { WAITV(0); }
    BARR;
  }

  // ---- epilogue: out += acc + bias (single writer, no atomics) ----
  float bv[4];
#pragma unroll
  for (int n = 0; n < 4; ++n)
    bv[n] = bias[tn + wc * 64 + (n >> 1) * 32 + (n & 1) * 16 + (l & 15)];
#pragma unroll
  for (int m = 0; m < 3; ++m) {
    const int row = tm + wr * 48 + m * 16 + (l >> 4) * 4;
#pragma unroll
    for (int n = 0; n < 4; ++n) {
      const int col = tn + wc * 64 + (n >> 1) * 32 + (n & 1) * 16 + (l & 15);
      float* po = outp + (size_t)row * EMBED + col;
#pragma unroll
      for (int ri = 0; ri < 4; ++ri)
        po[(size_t)ri * EMBED] += acc[m][n][ri] + bv[n];
    }
  }
}

// ---- launch -------------------------------------------------------------

extern "C" void kernel_launch(void* const* d_in, const int* in_sizes, int n_in,
                              void* d_out, int out_size, void* d_ws, size_t ws_size,
                              hipStream_t stream) {
  const float* xg[3] = {(const float*)d_in[0], (const float*)d_in[3], (const float*)d_in[6]};
  const float* mg[3] = {(const float*)d_in[1], (const float*)d_in[4], (const float*)d_in[7]};
  const float* tg[3] = {(const float*)d_in[2], (const float*)d_in[5], (const float*)d_in[8]};
  const int* idxg[3] = {(const int*)d_in[9], (const int*)d_in[10], (const int*)d_in[11]};
  const float* W_lin = (const float*)d_in[12];
  const float* b_lin = (const float*)d_in[13];
  const float* W_res = (const float*)d_in[14];
  const float* b_res = (const float*)d_in[15];
  const float* W_out = (const float*)d_in[16];
  const float* b_out = (const float*)d_in[17];
  float* out = (float*)d_out;

  char* ws = (char*)d_ws;
  size_t off = 0;
  auto alloc = [&](size_t b) -> char* {
    size_t o = (off + 255) & ~(size_t)255;
    off = o + b;
    return ws + o;
  };

  ushort_t* hidden = (ushort_t*)alloc((size_t)MROWS * INTER * 2);   // 201 MB
  const int Ps[3] = {16, 32, 64};
  const int Kp[3] = {64, 96, 192};
  ushort_t* xsw[3];
  ushort_t* wcat[3];
  for (int g = 0; g < 3; ++g) xsw[g]  = (ushort_t*)alloc((size_t)8192 * Kp[g] * 2);
  for (int g = 0; g < 3; ++g) wcat[g] = (ushort_t*)alloc((size_t)NCAT * Kp[g] * 2);
  ushort_t* wout = (ushort_t*)alloc((size_t)EMBED * INTER * 2);     // 8 MB
  float* bcat = (float*)alloc((size_t)NCAT * 4);

  prep_bcat<<<(NCAT + 255) / 256, 256, 0, stream>>>(b_lin, b_res, bcat);
  prep_wout<<<(EMBED * INTER) / 256, 256, 0, stream>>>(W_out, wout);
  for (int g = 0; g < 3; ++g) {
    int tw = NCAT * Kp[g];
    prep_wcat<<<(tw + 255) / 256, 256, 0, stream>>>(W_lin, W_res, wcat[g], 3 * Ps[g], Kp[g]);
    int tx = 8192 * Kp[g];
    prep_xs<<<(tx + 255) / 256, 256, 0, stream>>>(xg[g], mg[g], tg[g], xsw[g], Ps[g], Kp[g]);
  }
  // phase 1: all 3 groups in ONE dispatch: [8192 x Kp] @ [5120 x Kp]^T each
  gemm128p1g<<<dim3(192, 40), 256, 0, stream>>>(
      xsw[0], xsw[1], xsw[2], wcat[0], wcat[1], wcat[2], bcat,
      hidden, out, idxg[0], idxg[1], idxg[2]);
  // phase 2: [24576 x 4096] @ [1024 x 4096]^T, full K, out += acc + b_out
  gemm192n128<<<dim3(1024), 512, 0, stream>>>(hidden, wout, b_out, out);
}

// Round 9
// 380.182 us; speedup vs baseline: 1.3403x; 1.0679x over previous
//
#include <hip/hip_runtime.h>
#include <hip/hip_bf16.h>
#include <math.h>

typedef unsigned short ushort_t;
typedef short short8 __attribute__((ext_vector_type(8)));
typedef float f32x4 __attribute__((ext_vector_type(4)));

#define N_TOK 512
#define EMBED 1024
#define INTER 4096
#define NCAT  5120   /* INTER + EMBED */
#define MROWS 24576  /* 48 * 512 */

__device__ __forceinline__ ushort_t f2bf(float f) {
  union { float f; unsigned int u; } c; c.f = f;
  unsigned int u = c.u;
  unsigned int r = u + 0x7fffu + ((u >> 16) & 1u);
  return (ushort_t)(r >> 16);
}

__device__ __forceinline__ void gld_lds16(const void* g, void* l) {
  __builtin_amdgcn_global_load_lds(
      (const __attribute__((address_space(1))) void*)g,
      (__attribute__((address_space(3))) void*)l, 16, 0, 0);
}

// ---- prep kernels -------------------------------------------------------

__global__ void prep_bcat(const float* __restrict__ bl, const float* __restrict__ br,
                          float* __restrict__ dst) {
  int i = blockIdx.x * 256 + threadIdx.x;
  if (i >= NCAT) return;
  dst[i] = (i < INTER) ? bl[i] : br[i - INTER];
}

__global__ void prep_wout(const float* __restrict__ W, ushort_t* __restrict__ dst) {
  int i = blockIdx.x * 256 + threadIdx.x;   // total EMBED*INTER, exact grid
  dst[i] = f2bf(W[i]);
}

__global__ void prep_wcat(const float* __restrict__ Wl, const float* __restrict__ Wr,
                          ushort_t* __restrict__ dst, int P3, int Kpad) {
  int i = blockIdx.x * 256 + threadIdx.x;
  int total = NCAT * Kpad;
  if (i >= total) return;
  int r = i / Kpad, j = i - r * Kpad;
  float v = 0.f;
  if (j < P3) {
    float scale = 96.0f / (float)P3;
    float src = (j + 0.5f) * scale - 0.5f;
    src = fminf(fmaxf(src, 0.0f), 95.0f);
    int i0 = (int)src;
    int i1 = min(i0 + 1, 95);
    float tt = src - (float)i0;
    const float* Wrow = (r < INTER) ? (Wl + (size_t)r * 96)
                                    : (Wr + (size_t)(r - INTER) * 96);
    v = Wrow[i0] * (1.f - tt) + Wrow[i1] * tt;
  }
  dst[i] = f2bf(v);
}

__global__ void prep_xs(const float* __restrict__ x, const float* __restrict__ m,
                        const float* __restrict__ t, ushort_t* __restrict__ dst,
                        int p, int Kpad) {
  int i = blockIdx.x * 256 + threadIdx.x;
  int total = 8192 * Kpad;
  if (i >= total) return;
  int r = i / Kpad, j = i - r * Kpad;
  float v = 0.f;
  int p3 = 3 * p;
  if (j < p3) {
    size_t base = (size_t)r * p;
    if (j < p)           v = x[base + j];
    else if (j < 2 * p)  v = m[base + j - p];
    else                 v = t[base + j - 2 * p];
  }
  dst[i] = f2bf(v);
}

// ---- phase-1: merged 3-group 128x128 GEMM (R3/R7 interior, proven) ------
__global__ __launch_bounds__(256)
void gemm128p1g(const ushort_t* __restrict__ A0, const ushort_t* __restrict__ A1,
                const ushort_t* __restrict__ A2,
                const ushort_t* __restrict__ B0w, const ushort_t* __restrict__ B1w,
                const ushort_t* __restrict__ B2w,
                const float* __restrict__ bias,
                ushort_t* __restrict__ hidden, float* __restrict__ outp,
                const int* __restrict__ i0, const int* __restrict__ i1,
                const int* __restrict__ i2) {
  __shared__ __align__(16) ushort_t lA[2][128 * 32];
  __shared__ __align__(16) ushort_t lB[2][128 * 32];
  const int t = threadIdx.x;
  const int wave = t >> 6, lane = t & 63;
  const int gm = blockIdx.x >> 6;             // group 0/1/2
  const int tm = (blockIdx.x & 63) * 128;     // within-group row tile
  const int tn = blockIdx.y * 128;
  const ushort_t* A = (gm == 0) ? A0 : (gm == 1) ? A1 : A2;
  const ushort_t* B = (gm == 0) ? B0w : (gm == 1) ? B1w : B2w;
  const int* idxg   = (gm == 0) ? i0 : (gm == 1) ? i1 : i2;
  const int Kpad    = (gm == 0) ? 64 : (gm == 1) ? 96 : 192;

  const int chunk = wave * 2;
  const int srow = chunk * 16 + (lane >> 2);
  const int scol = (((lane & 3) ^ ((lane >> 3) & 3)) * 8);
  const ushort_t* gA0 = A + (size_t)(tm + srow) * Kpad + scol;
  const ushort_t* gA1 = gA0 + (size_t)16 * Kpad;
  const ushort_t* gB0 = B + (size_t)(tn + srow) * Kpad + scol;
  const ushort_t* gB1 = gB0 + (size_t)16 * Kpad;
  const int ldsOff0 = chunk * 512;
  const int ldsOff1 = ldsOff0 + 512;

  const int wr = wave >> 1, wc = wave & 1;
  const f32x4 zero = {0.f, 0.f, 0.f, 0.f};
  f32x4 acc[4][4];
#pragma unroll
  for (int m2 = 0; m2 < 4; ++m2)
#pragma unroll
    for (int n2 = 0; n2 < 4; ++n2) acc[m2][n2] = zero;

  const int xf = ((lane & 15) >> 1) & 3;
  const int fcol = (((lane >> 4) ^ xf)) * 8;
  const int aoff = (wr * 64 + (lane & 15)) * 32 + fcol;
  const int boff = (wc * 64 + (lane & 15)) * 32 + fcol;

  const int nk = Kpad >> 5;
  gld_lds16(gA0, &lA[0][ldsOff0]); gld_lds16(gA1, &lA[0][ldsOff1]);
  gld_lds16(gB0, &lB[0][ldsOff0]); gld_lds16(gB1, &lB[0][ldsOff1]);
  gA0 += 32; gA1 += 32; gB0 += 32; gB1 += 32;

  for (int kk = 0; kk < nk; ++kk) {
    const int cur = kk & 1;
    if (kk + 1 < nk) {
      const int nxt = cur ^ 1;
      gld_lds16(gA0, &lA[nxt][ldsOff0]); gld_lds16(gA1, &lA[nxt][ldsOff1]);
      gld_lds16(gB0, &lB[nxt][ldsOff0]); gld_lds16(gB1, &lB[nxt][ldsOff1]);
      gA0 += 32; gA1 += 32; gB0 += 32; gB1 += 32;
      asm volatile("s_waitcnt vmcnt(4)" ::: "memory");
    } else {
      asm volatile("s_waitcnt vmcnt(0)" ::: "memory");
    }
    __builtin_amdgcn_s_barrier();
    asm volatile("" ::: "memory");

    const ushort_t* pa = &lA[cur][0] + aoff;
    const ushort_t* pb = &lB[cur][0] + boff;
    short8 aF[4], bF[4];
#pragma unroll
    for (int m2 = 0; m2 < 4; ++m2) aF[m2] = *(const short8*)(pa + m2 * 16 * 32);
#pragma unroll
    for (int n2 = 0; n2 < 4; ++n2) bF[n2] = *(const short8*)(pb + n2 * 16 * 32);
#pragma unroll
    for (int m2 = 0; m2 < 4; ++m2)
#pragma unroll
      for (int n2 = 0; n2 < 4; ++n2)
        acc[m2][n2] = __builtin_amdgcn_mfma_f32_16x16x32_bf16(
            aF[m2], bF[n2], acc[m2][n2], 0, 0, 0);
    __builtin_amdgcn_s_barrier();
    asm volatile("" ::: "memory");
  }

  const int layer = idxg[tm >> 9];
  const int rowBase = layer * N_TOK + (tm & (N_TOK - 1));

#pragma unroll
  for (int m2 = 0; m2 < 4; ++m2) {
#pragma unroll
    for (int n2 = 0; n2 < 4; ++n2) {
      const int colg = tn + wc * 64 + n2 * 16 + (lane & 15);
      const float bv = bias[colg];
#pragma unroll
      for (int r = 0; r < 4; ++r) {
        const int rowl = wr * 64 + m2 * 16 + (lane >> 4) * 4 + r;
        const float v = acc[m2][n2][r];
        const int grow = rowBase + rowl;
        if (colg < INTER) {
          float h = v + bv;
          h = h / (1.f + expf(-h));
          hidden[(size_t)grow * INTER + colg] = f2bf(h);
        } else {
          outp[(size_t)grow * EMBED + (colg - INTER)] = v + bv;
        }
      }
    }
  }
}

// ---- phase-2: 192x128 full-K GEMM, 4 waves x 96x64 wave-tile -----------
// Same geometry/LDS-layout/swizzle/grid as R8 (2 blocks/CU, 80KB LDS),
// but 256 thr / 4 waves (2M x 2N), wave tile 96x64: reads/thread/KT
// A12+B8=20 (vs 28), MFMA 48 (vs 24) -> LDS pipe ~= MFMA pipe (balanced).
// Ledger (10 loads/KT/thread = A6+B4), KT t in buf t&1:
//   prologue: A0,B0 -> buf0; A1 -> buf1; vmcnt(6); BARR
//   ph1: LDA12+LDB4(nh0); stage B(t+1) -> buf^1; BARR;LGKM0; 24 MFMA; BARR
//   ph2: LDB4(nh1); stage A(t+2) -> buf; BARR;LGKM0; 24 MFMA;
//        vmcnt(6) [drains A(t+1),B(t+1); leaves A(t+2)]; BARR
#define P2BUF 40960
#define P2BOFF 24576

__global__ __launch_bounds__(256, 2)
void gemm192x128(const ushort_t* __restrict__ A, const ushort_t* __restrict__ Bw,
                 const float* __restrict__ bias, float* __restrict__ outp) {
  __shared__ __align__(16) char smem[2 * P2BUF];
  const int tid = threadIdx.x;
  const int w = tid >> 6, l = tid & 63;

  const int L = blockIdx.x;
  const int xcd = L & 7, j = L >> 3;          // j in [0,128)
  const int nt = j & 7, mtl = j >> 3;         // nt fastest: A-slab reuse
  const int tm = (xcd * 16 + mtl) * 192, tn = nt * 128;

  // staging source pointers (pre-swizzled global, linear LDS dest)
  const ushort_t* pA[6]; int dA[6];
#pragma unroll
  for (int jj = 0; jj < 6; ++jj) {
    const int q = w * 6 + jj;                 // 0..23
    const int ks = q / 12, rb = q % 12;
    const int row = rb * 16 + (l >> 2);
    const int c = (l & 3) ^ ((row >> 1) & 3);
    pA[jj] = A + (size_t)(tm + row) * 4096 + ks * 32 + c * 8;
    dA[jj] = ks * 12288 + rb * 1024;
  }
  const ushort_t* pB[4]; int dB[4];
#pragma unroll
  for (int jj = 0; jj < 4; ++jj) {
    const int q = w * 4 + jj;                 // 0..15
    const int ks = q >> 3, rb = q & 7;
    const int row = rb * 16 + (l >> 2);
    const int c = (l & 3) ^ ((row >> 1) & 3);
    pB[jj] = Bw + (size_t)(tn + row) * 4096 + ks * 32 + c * 8;
    dB[jj] = P2BOFF + ks * 8192 + rb * 1024;
  }

#define STGA6(BB) do { _Pragma("unroll") for (int jj = 0; jj < 6; ++jj) \
    gld_lds16(pA[jj], smem + (BB) + dA[jj]); \
    _Pragma("unroll") for (int jj = 0; jj < 6; ++jj) pA[jj] += 64; } while (0)
#define STGB4(BB) do { _Pragma("unroll") for (int jj = 0; jj < 4; ++jj) \
    gld_lds16(pB[jj], smem + (BB) + dB[jj]); \
    _Pragma("unroll") for (int jj = 0; jj < 4; ++jj) pB[jj] += 64; } while (0)

  // fragment read bases (swizzled read, conflict-free)
  const int wr = w >> 1, wc = w & 1;          // 2M x 2N
  const int xl = ((l & 15) >> 1) & 3;
  const int cx = ((l >> 4) ^ xl) * 16;
  const int aBase = (wr * 96 + (l & 15)) * 64 + cx;
  const int bBase = P2BOFF + (wc * 64 + (l & 15)) * 64 + cx;

  f32x4 acc[6][4];
  const f32x4 zero = {0.f, 0.f, 0.f, 0.f};
#pragma unroll
  for (int m = 0; m < 6; ++m)
#pragma unroll
    for (int n = 0; n < 4; ++n) acc[m][n] = zero;
  short8 aF[6][2], bF[2][2];

#define LDA12(BB) do { _Pragma("unroll") for (int mp = 0; mp < 6; ++mp) { \
    _Pragma("unroll") for (int ks = 0; ks < 2; ++ks) \
      aF[mp][ks] = *(const short8*)(smem + (BB) + ks * 12288 + mp * 1024 + aBase); } } while (0)
#define LDB4(BB, NH) do { _Pragma("unroll") for (int np = 0; np < 2; ++np) { \
    _Pragma("unroll") for (int ks = 0; ks < 2; ++ks) \
      bF[np][ks] = *(const short8*)(smem + (BB) + ks * 8192 + (NH) * 2048 + np * 1024 + bBase); } } while (0)
#define QUAD24(NH) do { _Pragma("unroll") for (int mp = 0; mp < 6; ++mp) { \
    _Pragma("unroll") for (int np = 0; np < 2; ++np) { \
      _Pragma("unroll") for (int ks = 0; ks < 2; ++ks) \
        acc[mp][(NH)*2+np] = __builtin_amdgcn_mfma_f32_16x16x32_bf16( \
            aF[mp][ks], bF[np][ks], acc[mp][(NH)*2+np], 0, 0, 0); } } } while (0)
#define BARR do { __builtin_amdgcn_s_barrier(); asm volatile("" ::: "memory"); } while (0)
#define LGKM0 do { asm volatile("s_waitcnt lgkmcnt(0)" ::: "memory"); \
    __builtin_amdgcn_sched_barrier(0); } while (0)
#define WAITV(N) do { asm volatile("s_waitcnt vmcnt(" #N ")" ::: "memory"); \
    __builtin_amdgcn_sched_barrier(0); } while (0)
#define PRIO1 __builtin_amdgcn_s_setprio(1)
#define PRIO0 __builtin_amdgcn_s_setprio(0)

  // prologue: A0,B0 -> buf0; A1 -> buf1; drain KT0 (leave A1 in flight)
  STGA6(0); STGB4(0);
  STGA6(P2BUF);
  WAITV(6);
  BARR;

  const int nit2 = 32;                         // 64 KTs, 2 per iteration
  for (int t2 = 0; t2 < nit2; ++t2) {
    const bool morA = (t2 + 1 < nit2);
    // ---- KT even (buf0) ----
    LDA12(0); LDB4(0, 0);
    STGB4(P2BUF);                              // B(t+1) -> buf1
    BARR; LGKM0; PRIO1; QUAD24(0); PRIO0; BARR;
    LDB4(0, 1);
    if (morA) STGA6(0);                        // A(t+2) -> buf0
    BARR; LGKM0; PRIO1; QUAD24(1); PRIO0;
    if (morA) { WAITV(6); } else { WAITV(0); } // drain A(t+1)+B(t+1)
    BARR;
    // ---- KT odd (buf1) ----
    LDA12(P2BUF); LDB4(P2BUF, 0);
    if (morA) STGB4(0);                        // B(t+2) -> buf0
    BARR; LGKM0; PRIO1; QUAD24(0); PRIO0; BARR;
    LDB4(P2BUF, 1);
    if (morA) STGA6(P2BUF);                    // A(t+3) -> buf1
    BARR; LGKM0; PRIO1; QUAD24(1); PRIO0;
    if (morA) { WAITV(6); } else { WAITV(0); }
    BARR;
  }

  // ---- epilogue: out += acc + bias (single writer, no atomics) ----
  float bv[4];
#pragma unroll
  for (int n = 0; n < 4; ++n)
    bv[n] = bias[tn + wc * 64 + (n >> 1) * 32 + (n & 1) * 16 + (l & 15)];
#pragma unroll
  for (int m = 0; m < 6; ++m) {
    const int row = tm + wr * 96 + m * 16 + (l >> 4) * 4;
#pragma unroll
    for (int n = 0; n < 4; ++n) {
      const int col = tn + wc * 64 + (n >> 1) * 32 + (n & 1) * 16 + (l & 15);
      float* po = outp + (size_t)row * EMBED + col;
#pragma unroll
      for (int ri = 0; ri < 4; ++ri)
        po[(size_t)ri * EMBED] += acc[m][n][ri] + bv[n];
    }
  }
}

// ---- launch -------------------------------------------------------------

extern "C" void kernel_launch(void* const* d_in, const int* in_sizes, int n_in,
                              void* d_out, int out_size, void* d_ws, size_t ws_size,
                              hipStream_t stream) {
  const float* xg[3] = {(const float*)d_in[0], (const float*)d_in[3], (const float*)d_in[6]};
  const float* mg[3] = {(const float*)d_in[1], (const float*)d_in[4], (const float*)d_in[7]};
  const float* tg[3] = {(const float*)d_in[2], (const float*)d_in[5], (const float*)d_in[8]};
  const int* idxg[3] = {(const int*)d_in[9], (const int*)d_in[10], (const int*)d_in[11]};
  const float* W_lin = (const float*)d_in[12];
  const float* b_lin = (const float*)d_in[13];
  const float* W_res = (const float*)d_in[14];
  const float* b_res = (const float*)d_in[15];
  const float* W_out = (const float*)d_in[16];
  const float* b_out = (const float*)d_in[17];
  float* out = (float*)d_out;

  char* ws = (char*)d_ws;
  size_t off = 0;
  auto alloc = [&](size_t b) -> char* {
    size_t o = (off + 255) & ~(size_t)255;
    off = o + b;
    return ws + o;
  };

  ushort_t* hidden = (ushort_t*)alloc((size_t)MROWS * INTER * 2);   // 201 MB
  const int Ps[3] = {16, 32, 64};
  const int Kp[3] = {64, 96, 192};
  ushort_t* xsw[3];
  ushort_t* wcat[3];
  for (int g = 0; g < 3; ++g) xsw[g]  = (ushort_t*)alloc((size_t)8192 * Kp[g] * 2);
  for (int g = 0; g < 3; ++g) wcat[g] = (ushort_t*)alloc((size_t)NCAT * Kp[g] * 2);
  ushort_t* wout = (ushort_t*)alloc((size_t)EMBED * INTER * 2);     // 8 MB
  float* bcat = (float*)alloc((size_t)NCAT * 4);

  prep_bcat<<<(NCAT + 255) / 256, 256, 0, stream>>>(b_lin, b_res, bcat);
  prep_wout<<<(EMBED * INTER) / 256, 256, 0, stream>>>(W_out, wout);
  for (int g = 0; g < 3; ++g) {
    int tw = NCAT * Kp[g];
    prep_wcat<<<(tw + 255) / 256, 256, 0, stream>>>(W_lin, W_res, wcat[g], 3 * Ps[g], Kp[g]);
    int tx = 8192 * Kp[g];
    prep_xs<<<(tx + 255) / 256, 256, 0, stream>>>(xg[g], mg[g], tg[g], xsw[g], Ps[g], Kp[g]);
  }
  // phase 1: all 3 groups in ONE dispatch: [8192 x Kp] @ [5120 x Kp]^T each
  gemm128p1g<<<dim3(192, 40), 256, 0, stream>>>(
      xsw[0], xsw[1], xsw[2], wcat[0], wcat[1], wcat[2], bcat,
      hidden, out, idxg[0], idxg[1], idxg[2]);
  // phase 2: [24576 x 4096] @ [1024 x 4096]^T, full K, out += acc + b_out
  gemm192x128<<<dim3(1024), 256, 0, stream>>>(hidden, wout, b_out, out);
}

// Round 10
// 373.143 us; speedup vs baseline: 1.3656x; 1.0189x over previous
//
#include <hip/hip_runtime.h>
#include <hip/hip_bf16.h>
#include <math.h>

typedef unsigned short ushort_t;
typedef short short8 __attribute__((ext_vector_type(8)));
typedef float f32x4 __attribute__((ext_vector_type(4)));

#define N_TOK 512
#define EMBED 1024
#define INTER 4096
#define NCAT  5120   /* INTER + EMBED */
#define MROWS 24576  /* 48 * 512 */

__device__ __forceinline__ ushort_t f2bf(float f) {
  union { float f; unsigned int u; } c; c.f = f;
  unsigned int u = c.u;
  unsigned int r = u + 0x7fffu + ((u >> 16) & 1u);
  return (ushort_t)(r >> 16);
}

__device__ __forceinline__ void gld_lds16(const void* g, void* l) {
  __builtin_amdgcn_global_load_lds(
      (const __attribute__((address_space(1))) void*)g,
      (__attribute__((address_space(3))) void*)l, 16, 0, 0);
}

// ---- merged prep kernels ------------------------------------------------
// prep_w: flat index over [bcat | wout | wcat g0 | wcat g1 | wcat g2]
__global__ void prep_w(const float* __restrict__ Wl, const float* __restrict__ Wr,
                       const float* __restrict__ Wo,
                       const float* __restrict__ bl, const float* __restrict__ br,
                       ushort_t* __restrict__ wout,
                       ushort_t* __restrict__ w0, ushort_t* __restrict__ w1,
                       ushort_t* __restrict__ w2, float* __restrict__ bcat) {
  int i = blockIdx.x * 256 + threadIdx.x;
  if (i < NCAT) { bcat[i] = (i < INTER) ? bl[i] : br[i - INTER]; return; }
  i -= NCAT;
  if (i < EMBED * INTER) { wout[i] = f2bf(Wo[i]); return; }
  i -= EMBED * INTER;
  ushort_t* dst; int Kpad, P3;
  if (i < NCAT * 64)            { dst = w0; Kpad = 64;  P3 = 48; }
  else if (i < NCAT * 160)      { i -= NCAT * 64;  dst = w1; Kpad = 96;  P3 = 96; }
  else if (i < NCAT * 352)      { i -= NCAT * 160; dst = w2; Kpad = 192; P3 = 192; }
  else return;
  const int r = i / Kpad, j = i - r * Kpad;
  float v = 0.f;
  if (j < P3) {
    float scale = 96.0f / (float)P3;
    float src = (j + 0.5f) * scale - 0.5f;
    src = fminf(fmaxf(src, 0.0f), 95.0f);
    int i0 = (int)src;
    int i1 = min(i0 + 1, 95);
    float tt = src - (float)i0;
    const float* Wrow = (r < INTER) ? (Wl + (size_t)r * 96)
                                    : (Wr + (size_t)(r - INTER) * 96);
    v = Wrow[i0] * (1.f - tt) + Wrow[i1] * tt;
  }
  dst[i] = f2bf(v);
}

// prep_x: flat index over xs g0 | g1 | g2 (zero-padded bf16 [8192][Kpad])
__global__ void prep_x(const float* __restrict__ x0, const float* __restrict__ m0,
                       const float* __restrict__ t0,
                       const float* __restrict__ x1, const float* __restrict__ m1,
                       const float* __restrict__ t1,
                       const float* __restrict__ x2, const float* __restrict__ m2,
                       const float* __restrict__ t2,
                       ushort_t* __restrict__ d0, ushort_t* __restrict__ d1,
                       ushort_t* __restrict__ d2) {
  int i = blockIdx.x * 256 + threadIdx.x;
  const float *x, *m, *t; ushort_t* dst; int p, Kpad;
  if (i < 8192 * 64)            { x = x0; m = m0; t = t0; dst = d0; p = 16; Kpad = 64; }
  else if (i < 8192 * 160)      { i -= 8192 * 64;  x = x1; m = m1; t = t1; dst = d1; p = 32; Kpad = 96; }
  else if (i < 8192 * 352)      { i -= 8192 * 160; x = x2; m = m2; t = t2; dst = d2; p = 64; Kpad = 192; }
  else return;
  const int r = i / Kpad, j = i - r * Kpad;
  float v = 0.f;
  const int p3 = 3 * p;
  if (j < p3) {
    size_t base = (size_t)r * p;
    if (j < p)           v = x[base + j];
    else if (j < 2 * p)  v = m[base + j - p];
    else                 v = t[base + j - 2 * p];
  }
  dst[i] = f2bf(v);
}

// ---- phase-1: merged 3-group 128x128 GEMM (R3/R7 interior, proven) ------
__global__ __launch_bounds__(256)
void gemm128p1g(const ushort_t* __restrict__ A0, const ushort_t* __restrict__ A1,
                const ushort_t* __restrict__ A2,
                const ushort_t* __restrict__ B0w, const ushort_t* __restrict__ B1w,
                const ushort_t* __restrict__ B2w,
                const float* __restrict__ bias,
                ushort_t* __restrict__ hidden, float* __restrict__ outp,
                const int* __restrict__ i0, const int* __restrict__ i1,
                const int* __restrict__ i2) {
  __shared__ __align__(16) ushort_t lA[2][128 * 32];
  __shared__ __align__(16) ushort_t lB[2][128 * 32];
  const int t = threadIdx.x;
  const int wave = t >> 6, lane = t & 63;
  const int gm = blockIdx.x >> 6;             // group 0/1/2
  const int tm = (blockIdx.x & 63) * 128;     // within-group row tile
  const int tn = blockIdx.y * 128;
  const ushort_t* A = (gm == 0) ? A0 : (gm == 1) ? A1 : A2;
  const ushort_t* B = (gm == 0) ? B0w : (gm == 1) ? B1w : B2w;
  const int* idxg   = (gm == 0) ? i0 : (gm == 1) ? i1 : i2;
  const int Kpad    = (gm == 0) ? 64 : (gm == 1) ? 96 : 192;

  const int chunk = wave * 2;
  const int srow = chunk * 16 + (lane >> 2);
  const int scol = (((lane & 3) ^ ((lane >> 3) & 3)) * 8);
  const ushort_t* gA0 = A + (size_t)(tm + srow) * Kpad + scol;
  const ushort_t* gA1 = gA0 + (size_t)16 * Kpad;
  const ushort_t* gB0 = B + (size_t)(tn + srow) * Kpad + scol;
  const ushort_t* gB1 = gB0 + (size_t)16 * Kpad;
  const int ldsOff0 = chunk * 512;
  const int ldsOff1 = ldsOff0 + 512;

  const int wr = wave >> 1, wc = wave & 1;
  const f32x4 zero = {0.f, 0.f, 0.f, 0.f};
  f32x4 acc[4][4];
#pragma unroll
  for (int m2 = 0; m2 < 4; ++m2)
#pragma unroll
    for (int n2 = 0; n2 < 4; ++n2) acc[m2][n2] = zero;

  const int xf = ((lane & 15) >> 1) & 3;
  const int fcol = (((lane >> 4) ^ xf)) * 8;
  const int aoff = (wr * 64 + (lane & 15)) * 32 + fcol;
  const int boff = (wc * 64 + (lane & 15)) * 32 + fcol;

  const int nk = Kpad >> 5;
  gld_lds16(gA0, &lA[0][ldsOff0]); gld_lds16(gA1, &lA[0][ldsOff1]);
  gld_lds16(gB0, &lB[0][ldsOff0]); gld_lds16(gB1, &lB[0][ldsOff1]);
  gA0 += 32; gA1 += 32; gB0 += 32; gB1 += 32;

  for (int kk = 0; kk < nk; ++kk) {
    const int cur = kk & 1;
    if (kk + 1 < nk) {
      const int nxt = cur ^ 1;
      gld_lds16(gA0, &lA[nxt][ldsOff0]); gld_lds16(gA1, &lA[nxt][ldsOff1]);
      gld_lds16(gB0, &lB[nxt][ldsOff0]); gld_lds16(gB1, &lB[nxt][ldsOff1]);
      gA0 += 32; gA1 += 32; gB0 += 32; gB1 += 32;
      asm volatile("s_waitcnt vmcnt(4)" ::: "memory");
    } else {
      asm volatile("s_waitcnt vmcnt(0)" ::: "memory");
    }
    __builtin_amdgcn_s_barrier();
    asm volatile("" ::: "memory");

    const ushort_t* pa = &lA[cur][0] + aoff;
    const ushort_t* pb = &lB[cur][0] + boff;
    short8 aF[4], bF[4];
#pragma unroll
    for (int m2 = 0; m2 < 4; ++m2) aF[m2] = *(const short8*)(pa + m2 * 16 * 32);
#pragma unroll
    for (int n2 = 0; n2 < 4; ++n2) bF[n2] = *(const short8*)(pb + n2 * 16 * 32);
#pragma unroll
    for (int m2 = 0; m2 < 4; ++m2)
#pragma unroll
      for (int n2 = 0; n2 < 4; ++n2)
        acc[m2][n2] = __builtin_amdgcn_mfma_f32_16x16x32_bf16(
            aF[m2], bF[n2], acc[m2][n2], 0, 0, 0);
    __builtin_amdgcn_s_barrier();
    asm volatile("" ::: "memory");
  }

  const int layer = idxg[tm >> 9];
  const int rowBase = layer * N_TOK + (tm & (N_TOK - 1));

#pragma unroll
  for (int m2 = 0; m2 < 4; ++m2) {
#pragma unroll
    for (int n2 = 0; n2 < 4; ++n2) {
      const int colg = tn + wc * 64 + n2 * 16 + (lane & 15);
      const float bv = bias[colg];
#pragma unroll
      for (int r = 0; r < 4; ++r) {
        const int rowl = wr * 64 + m2 * 16 + (lane >> 4) * 4 + r;
        const float v = acc[m2][n2][r];
        const int grow = rowBase + rowl;
        if (colg < INTER) {
          float h = v + bv;
          h = h / (1.f + expf(-h));
          hidden[(size_t)grow * INTER + colg] = f2bf(h);
        } else {
          outp[(size_t)grow * EMBED + (colg - INTER)] = v + bv;
        }
      }
    }
  }
}

// ---- phase-2: 192x128 full-K GEMM, minimal-barrier schedule ------------
// R9 geometry (2 blocks/CU, 80KB LDS, 4 waves 96x64, 0-conflict swizzle)
// with the redundant leading barriers and forced lgkm drains removed:
// per KT: {20 ds_reads + stage B(t+1); MFMA(nh0); BARR; stage A(t+2);
//          MFMA(nh1); vmcnt(6); BARR}. Compiler emits minimal counted
// lgkm waits for read->MFMA deps (m97-verified). WAR proof: every stage
// follows the trailing barrier that sealed all cross-wave reads of the
// region it overwrites; MFMA operand consumption seals own-wave reads.
// FIFO invariant: entering KT t outstanding = A(t+1).6; +B(t+1).4
// +A(t+2).6 -> vmcnt(6) drains exactly KT(t+1)'s data. Tail: KT62
// stages B63 only, vmcnt(0); KT63 stages nothing.
#define P2BUF 40960
#define P2BOFF 24576

__global__ __launch_bounds__(256, 2)
void gemm192x128(const ushort_t* __restrict__ A, const ushort_t* __restrict__ Bw,
                 const float* __restrict__ bias, float* __restrict__ outp) {
  __shared__ __align__(16) char smem[2 * P2BUF];
  const int tid = threadIdx.x;
  const int w = tid >> 6, l = tid & 63;

  const int L = blockIdx.x;
  const int xcd = L & 7, j = L >> 3;          // j in [0,128)
  const int nt = j & 7, mtl = j >> 3;         // nt fastest: A-slab reuse
  const int tm = (xcd * 16 + mtl) * 192, tn = nt * 128;

  // staging source pointers (pre-swizzled global, linear LDS dest)
  const ushort_t* pA[6]; int dA[6];
#pragma unroll
  for (int jj = 0; jj < 6; ++jj) {
    const int q = w * 6 + jj;                 // 0..23
    const int ks = q / 12, rb = q % 12;
    const int row = rb * 16 + (l >> 2);
    const int c = (l & 3) ^ ((row >> 1) & 3);
    pA[jj] = A + (size_t)(tm + row) * 4096 + ks * 32 + c * 8;
    dA[jj] = ks * 12288 + rb * 1024;
  }
  const ushort_t* pB[4]; int dB[4];
#pragma unroll
  for (int jj = 0; jj < 4; ++jj) {
    const int q = w * 4 + jj;                 // 0..15
    const int ks = q >> 3, rb = q & 7;
    const int row = rb * 16 + (l >> 2);
    const int c = (l & 3) ^ ((row >> 1) & 3);
    pB[jj] = Bw + (size_t)(tn + row) * 4096 + ks * 32 + c * 8;
    dB[jj] = P2BOFF + ks * 8192 + rb * 1024;
  }

#define STGA6(BB) do { _Pragma("unroll") for (int jj = 0; jj < 6; ++jj) \
    gld_lds16(pA[jj], smem + (BB) + dA[jj]); \
    _Pragma("unroll") for (int jj = 0; jj < 6; ++jj) pA[jj] += 64; } while (0)
#define STGB4(BB) do { _Pragma("unroll") for (int jj = 0; jj < 4; ++jj) \
    gld_lds16(pB[jj], smem + (BB) + dB[jj]); \
    _Pragma("unroll") for (int jj = 0; jj < 4; ++jj) pB[jj] += 64; } while (0)

  // fragment read bases (swizzled read, conflict-free)
  const int wr = w >> 1, wc = w & 1;          // 2M x 2N
  const int xl = ((l & 15) >> 1) & 3;
  const int cx = ((l >> 4) ^ xl) * 16;
  const int aBase = (wr * 96 + (l & 15)) * 64 + cx;
  const int bBase = P2BOFF + (wc * 64 + (l & 15)) * 64 + cx;

  f32x4 acc[6][4];
  const f32x4 zero = {0.f, 0.f, 0.f, 0.f};
#pragma unroll
  for (int m = 0; m < 6; ++m)
#pragma unroll
    for (int n = 0; n < 4; ++n) acc[m][n] = zero;
  short8 aF[6][2], bF[2][2], bF2[2][2];

#define LDA12(BB) do { _Pragma("unroll") for (int mp = 0; mp < 6; ++mp) { \
    _Pragma("unroll") for (int ks = 0; ks < 2; ++ks) \
      aF[mp][ks] = *(const short8*)(smem + (BB) + ks * 12288 + mp * 1024 + aBase); } } while (0)
#define LDB4(D, BB, NH) do { _Pragma("unroll") for (int np = 0; np < 2; ++np) { \
    _Pragma("unroll") for (int ks = 0; ks < 2; ++ks) \
      D[np][ks] = *(const short8*)(smem + (BB) + ks * 8192 + (NH) * 2048 + np * 1024 + bBase); } } while (0)
#define QUAD24(NH, FB) do { _Pragma("unroll") for (int mp = 0; mp < 6; ++mp) { \
    _Pragma("unroll") for (int np = 0; np < 2; ++np) { \
      _Pragma("unroll") for (int ks = 0; ks < 2; ++ks) \
        acc[mp][(NH)*2+np] = __builtin_amdgcn_mfma_f32_16x16x32_bf16( \
            aF[mp][ks], FB[np][ks], acc[mp][(NH)*2+np], 0, 0, 0); } } } while (0)
#define BARR do { __builtin_amdgcn_s_barrier(); asm volatile("" ::: "memory"); } while (0)
#define WAITV(N) do { asm volatile("s_waitcnt vmcnt(" #N ")" ::: "memory"); \
    __builtin_amdgcn_sched_barrier(0); } while (0)
#define PRIO1 __builtin_amdgcn_s_setprio(1)
#define PRIO0 __builtin_amdgcn_s_setprio(0)

  // prologue: A0,B0 -> buf0; A1 -> buf1; drain KT0 (leave A1 in flight)
  STGA6(0); STGB4(0);
  STGA6(P2BUF);
  WAITV(6);
  BARR;

  const int nit2 = 32;                         // 64 KTs, 2 per iteration
  for (int t2 = 0; t2 < nit2; ++t2) {
    const bool morA = (t2 + 1 < nit2);
    // ---- KT even (buf0) ----
    LDA12(0); LDB4(bF, 0, 0); LDB4(bF2, 0, 1);
    STGB4(P2BUF);                              // B(t+1) -> buf1
    PRIO1; QUAD24(0, bF); PRIO0;
    BARR;                                      // seals all waves' buf0 reads
    if (morA) STGA6(0);                        // A(t+2) -> buf0
    PRIO1; QUAD24(1, bF2); PRIO0;
    if (morA) { WAITV(6); } else { WAITV(0); } // drain KT(t+1) data
    BARR;
    // ---- KT odd (buf1) ----
    LDA12(P2BUF); LDB4(bF, P2BUF, 0); LDB4(bF2, P2BUF, 1);
    if (morA) STGB4(0);                        // B(t+2) -> buf0
    PRIO1; QUAD24(0, bF); PRIO0;
    BARR;
    if (morA) STGA6(P2BUF);                    // A(t+3) -> buf1
    PRIO1; QUAD24(1, bF2); PRIO0;
    if (morA) { WAITV(6); } else { WAITV(0); }
    BARR;
  }

  // ---- epilogue: out += acc + bias (single writer, no atomics) ----
  float bv[4];
#pragma unroll
  for (int n = 0; n < 4; ++n)
    bv[n] = bias[tn + wc * 64 + (n >> 1) * 32 + (n & 1) * 16 + (l & 15)];
#pragma unroll
  for (int m = 0; m < 6; ++m) {
    const int row = tm + wr * 96 + m * 16 + (l >> 4) * 4;
#pragma unroll
    for (int n = 0; n < 4; ++n) {
      const int col = tn + wc * 64 + (n >> 1) * 32 + (n & 1) * 16 + (l & 15);
      float* po = outp + (size_t)row * EMBED + col;
#pragma unroll
      for (int ri = 0; ri < 4; ++ri)
        po[(size_t)ri * EMBED] += acc[m][n][ri] + bv[n];
    }
  }
}

// ---- launch -------------------------------------------------------------

extern "C" void kernel_launch(void* const* d_in, const int* in_sizes, int n_in,
                              void* d_out, int out_size, void* d_ws, size_t ws_size,
                              hipStream_t stream) {
  const float* xg[3] = {(const float*)d_in[0], (const float*)d_in[3], (const float*)d_in[6]};
  const float* mg[3] = {(const float*)d_in[1], (const float*)d_in[4], (const float*)d_in[7]};
  const float* tg[3] = {(const float*)d_in[2], (const float*)d_in[5], (const float*)d_in[8]};
  const int* idxg[3] = {(const int*)d_in[9], (const int*)d_in[10], (const int*)d_in[11]};
  const float* W_lin = (const float*)d_in[12];
  const float* b_lin = (const float*)d_in[13];
  const float* W_res = (const float*)d_in[14];
  const float* b_res = (const float*)d_in[15];
  const float* W_out = (const float*)d_in[16];
  const float* b_out = (const float*)d_in[17];
  float* out = (float*)d_out;

  char* ws = (char*)d_ws;
  size_t off = 0;
  auto alloc = [&](size_t b) -> char* {
    size_t o = (off + 255) & ~(size_t)255;
    off = o + b;
    return ws + o;
  };

  ushort_t* hidden = (ushort_t*)alloc((size_t)MROWS * INTER * 2);   // 201 MB
  const int Kp[3] = {64, 96, 192};
  ushort_t* xsw[3];
  ushort_t* wcat[3];
  for (int g = 0; g < 3; ++g) xsw[g]  = (ushort_t*)alloc((size_t)8192 * Kp[g] * 2);
  for (int g = 0; g < 3; ++g) wcat[g] = (ushort_t*)alloc((size_t)NCAT * Kp[g] * 2);
  ushort_t* wout = (ushort_t*)alloc((size_t)EMBED * INTER * 2);     // 8 MB
  float* bcat = (float*)alloc((size_t)NCAT * 4);

  // merged preps: 2 dispatches
  const int wTotal = NCAT + EMBED * INTER + NCAT * 352;   // 6,001,664
  prep_w<<<(wTotal + 255) / 256, 256, 0, stream>>>(
      W_lin, W_res, W_out, b_lin, b_res, wout, wcat[0], wcat[1], wcat[2], bcat);
  const int xTotal = 8192 * 352;                          // 2,883,584
  prep_x<<<(xTotal + 255) / 256, 256, 0, stream>>>(
      xg[0], mg[0], tg[0], xg[1], mg[1], tg[1], xg[2], mg[2], tg[2],
      xsw[0], xsw[1], xsw[2]);

  // phase 1: all 3 groups in ONE dispatch: [8192 x Kp] @ [5120 x Kp]^T each
  gemm128p1g<<<dim3(192, 40), 256, 0, stream>>>(
      xsw[0], xsw[1], xsw[2], wcat[0], wcat[1], wcat[2], bcat,
      hidden, out, idxg[0], idxg[1], idxg[2]);
  // phase 2: [24576 x 4096] @ [1024 x 4096]^T, full K, out += acc + b_out
  gemm192x128<<<dim3(1024), 256, 0, stream>>>(hidden, wout, b_out, out);
}

// Round 11
// 370.522 us; speedup vs baseline: 1.3752x; 1.0071x over previous
//
#include <hip/hip_runtime.h>
#include <hip/hip_bf16.h>
#include <math.h>

typedef unsigned short ushort_t;
typedef short short8 __attribute__((ext_vector_type(8)));
typedef float f32x4 __attribute__((ext_vector_type(4)));

#define N_TOK 512
#define EMBED 1024
#define INTER 4096
#define NCAT  5120   /* INTER + EMBED */
#define MROWS 24576  /* 48 * 512 */

__device__ __forceinline__ ushort_t f2bf(float f) {
  union { float f; unsigned int u; } c; c.f = f;
  unsigned int u = c.u;
  unsigned int r = u + 0x7fffu + ((u >> 16) & 1u);
  return (ushort_t)(r >> 16);
}

__device__ __forceinline__ void gld_lds16(const void* g, void* l) {
  __builtin_amdgcn_global_load_lds(
      (const __attribute__((address_space(1))) void*)g,
      (__attribute__((address_space(3))) void*)l, 16, 0, 0);
}

// ---- merged prep kernels ------------------------------------------------
__global__ void prep_w(const float* __restrict__ Wl, const float* __restrict__ Wr,
                       const float* __restrict__ Wo,
                       const float* __restrict__ bl, const float* __restrict__ br,
                       ushort_t* __restrict__ wout,
                       ushort_t* __restrict__ w0, ushort_t* __restrict__ w1,
                       ushort_t* __restrict__ w2, float* __restrict__ bcat) {
  int i = blockIdx.x * 256 + threadIdx.x;
  if (i < NCAT) { bcat[i] = (i < INTER) ? bl[i] : br[i - INTER]; return; }
  i -= NCAT;
  if (i < EMBED * INTER) { wout[i] = f2bf(Wo[i]); return; }
  i -= EMBED * INTER;
  ushort_t* dst; int Kpad, P3;
  if (i < NCAT * 64)            { dst = w0; Kpad = 64;  P3 = 48; }
  else if (i < NCAT * 160)      { i -= NCAT * 64;  dst = w1; Kpad = 96;  P3 = 96; }
  else if (i < NCAT * 352)      { i -= NCAT * 160; dst = w2; Kpad = 192; P3 = 192; }
  else return;
  const int r = i / Kpad, j = i - r * Kpad;
  float v = 0.f;
  if (j < P3) {
    float scale = 96.0f / (float)P3;
    float src = (j + 0.5f) * scale - 0.5f;
    src = fminf(fmaxf(src, 0.0f), 95.0f);
    int i0 = (int)src;
    int i1 = min(i0 + 1, 95);
    float tt = src - (float)i0;
    const float* Wrow = (r < INTER) ? (Wl + (size_t)r * 96)
                                    : (Wr + (size_t)(r - INTER) * 96);
    v = Wrow[i0] * (1.f - tt) + Wrow[i1] * tt;
  }
  dst[i] = f2bf(v);
}

__global__ void prep_x(const float* __restrict__ x0, const float* __restrict__ m0,
                       const float* __restrict__ t0,
                       const float* __restrict__ x1, const float* __restrict__ m1,
                       const float* __restrict__ t1,
                       const float* __restrict__ x2, const float* __restrict__ m2,
                       const float* __restrict__ t2,
                       ushort_t* __restrict__ d0, ushort_t* __restrict__ d1,
                       ushort_t* __restrict__ d2) {
  int i = blockIdx.x * 256 + threadIdx.x;
  const float *x, *m, *t; ushort_t* dst; int p, Kpad;
  if (i < 8192 * 64)            { x = x0; m = m0; t = t0; dst = d0; p = 16; Kpad = 64; }
  else if (i < 8192 * 160)      { i -= 8192 * 64;  x = x1; m = m1; t = t1; dst = d1; p = 32; Kpad = 96; }
  else if (i < 8192 * 352)      { i -= 8192 * 160; x = x2; m = m2; t = t2; dst = d2; p = 64; Kpad = 192; }
  else return;
  const int r = i / Kpad, j = i - r * Kpad;
  float v = 0.f;
  const int p3 = 3 * p;
  if (j < p3) {
    size_t base = (size_t)r * p;
    if (j < p)           v = x[base + j];
    else if (j < 2 * p)  v = m[base + j - p];
    else                 v = t[base + j - 2 * p];
  }
  dst[i] = f2bf(v);
}

// ---- phase-1: merged 3-group 128x128 GEMM (R3/R7 interior, proven) ------
__global__ __launch_bounds__(256)
void gemm128p1g(const ushort_t* __restrict__ A0, const ushort_t* __restrict__ A1,
                const ushort_t* __restrict__ A2,
                const ushort_t* __restrict__ B0w, const ushort_t* __restrict__ B1w,
                const ushort_t* __restrict__ B2w,
                const float* __restrict__ bias,
                ushort_t* __restrict__ hidden, float* __restrict__ outp,
                const int* __restrict__ i0, const int* __restrict__ i1,
                const int* __restrict__ i2) {
  __shared__ __align__(16) ushort_t lA[2][128 * 32];
  __shared__ __align__(16) ushort_t lB[2][128 * 32];
  const int t = threadIdx.x;
  const int wave = t >> 6, lane = t & 63;
  const int gm = blockIdx.x >> 6;             // group 0/1/2
  const int tm = (blockIdx.x & 63) * 128;     // within-group row tile
  const int tn = blockIdx.y * 128;
  const ushort_t* A = (gm == 0) ? A0 : (gm == 1) ? A1 : A2;
  const ushort_t* B = (gm == 0) ? B0w : (gm == 1) ? B1w : B2w;
  const int* idxg   = (gm == 0) ? i0 : (gm == 1) ? i1 : i2;
  const int Kpad    = (gm == 0) ? 64 : (gm == 1) ? 96 : 192;

  const int chunk = wave * 2;
  const int srow = chunk * 16 + (lane >> 2);
  const int scol = (((lane & 3) ^ ((lane >> 3) & 3)) * 8);
  const ushort_t* gA0 = A + (size_t)(tm + srow) * Kpad + scol;
  const ushort_t* gA1 = gA0 + (size_t)16 * Kpad;
  const ushort_t* gB0 = B + (size_t)(tn + srow) * Kpad + scol;
  const ushort_t* gB1 = gB0 + (size_t)16 * Kpad;
  const int ldsOff0 = chunk * 512;
  const int ldsOff1 = ldsOff0 + 512;

  const int wr = wave >> 1, wc = wave & 1;
  const f32x4 zero = {0.f, 0.f, 0.f, 0.f};
  f32x4 acc[4][4];
#pragma unroll
  for (int m2 = 0; m2 < 4; ++m2)
#pragma unroll
    for (int n2 = 0; n2 < 4; ++n2) acc[m2][n2] = zero;

  const int xf = ((lane & 15) >> 1) & 3;
  const int fcol = (((lane >> 4) ^ xf)) * 8;
  const int aoff = (wr * 64 + (lane & 15)) * 32 + fcol;
  const int boff = (wc * 64 + (lane & 15)) * 32 + fcol;

  const int nk = Kpad >> 5;
  gld_lds16(gA0, &lA[0][ldsOff0]); gld_lds16(gA1, &lA[0][ldsOff1]);
  gld_lds16(gB0, &lB[0][ldsOff0]); gld_lds16(gB1, &lB[0][ldsOff1]);
  gA0 += 32; gA1 += 32; gB0 += 32; gB1 += 32;

  for (int kk = 0; kk < nk; ++kk) {
    const int cur = kk & 1;
    if (kk + 1 < nk) {
      const int nxt = cur ^ 1;
      gld_lds16(gA0, &lA[nxt][ldsOff0]); gld_lds16(gA1, &lA[nxt][ldsOff1]);
      gld_lds16(gB0, &lB[nxt][ldsOff0]); gld_lds16(gB1, &lB[nxt][ldsOff1]);
      gA0 += 32; gA1 += 32; gB0 += 32; gB1 += 32;
      asm volatile("s_waitcnt vmcnt(4)" ::: "memory");
    } else {
      asm volatile("s_waitcnt vmcnt(0)" ::: "memory");
    }
    __builtin_amdgcn_s_barrier();
    asm volatile("" ::: "memory");

    const ushort_t* pa = &lA[cur][0] + aoff;
    const ushort_t* pb = &lB[cur][0] + boff;
    short8 aF[4], bF[4];
#pragma unroll
    for (int m2 = 0; m2 < 4; ++m2) aF[m2] = *(const short8*)(pa + m2 * 16 * 32);
#pragma unroll
    for (int n2 = 0; n2 < 4; ++n2) bF[n2] = *(const short8*)(pb + n2 * 16 * 32);
#pragma unroll
    for (int m2 = 0; m2 < 4; ++m2)
#pragma unroll
      for (int n2 = 0; n2 < 4; ++n2)
        acc[m2][n2] = __builtin_amdgcn_mfma_f32_16x16x32_bf16(
            aF[m2], bF[n2], acc[m2][n2], 0, 0, 0);
    __builtin_amdgcn_s_barrier();
    asm volatile("" ::: "memory");
  }

  const int layer = idxg[tm >> 9];
  const int rowBase = layer * N_TOK + (tm & (N_TOK - 1));

#pragma unroll
  for (int m2 = 0; m2 < 4; ++m2) {
#pragma unroll
    for (int n2 = 0; n2 < 4; ++n2) {
      const int colg = tn + wc * 64 + n2 * 16 + (lane & 15);
      const float bv = bias[colg];
#pragma unroll
      for (int r = 0; r < 4; ++r) {
        const int rowl = wr * 64 + m2 * 16 + (lane >> 4) * 4 + r;
        const float v = acc[m2][n2][r];
        const int grow = rowBase + rowl;
        if (colg < INTER) {
          float h = v + bv;
          h = h / (1.f + expf(-h));
          hidden[(size_t)grow * INTER + colg] = f2bf(h);
        } else {
          outp[(size_t)grow * EMBED + (colg - INTER)] = v + bv;
        }
      }
    }
  }
}

// ---- phase-2: 192x128 full-K GEMM, anti-phase K-rotation ---------------
// R10 structure (2 blocks/CU, 80KB LDS, 4 waves 96x64, 0-conflict swizzle,
// minimal-barrier schedule, proven vmcnt(6) ledger) + ONE change: adjacent
// same-XCD blocks traverse the 64 K-tiles starting 32 apart
// (rot = ((L>>3)&1)*32). Full-K accumulation is K-order-invariant, so only
// the stage-time global offsets change: offA/offB advance by 64 elements
// per staged KT with wrap (off+64)&4095. Goal: co-resident blocks sit in
// ANTI-phase (one block's read-burst overlaps the other's MFMA burst)
// instead of phase-locking -> LDS and MFMA pipes run concurrently.
#define P2BUF 40960
#define P2BOFF 24576

__global__ __launch_bounds__(256, 2)
void gemm192x128(const ushort_t* __restrict__ A, const ushort_t* __restrict__ Bw,
                 const float* __restrict__ bias, float* __restrict__ outp) {
  __shared__ __align__(16) char smem[2 * P2BUF];
  const int tid = threadIdx.x;
  const int w = tid >> 6, l = tid & 63;

  const int L = blockIdx.x;
  const int xcd = L & 7, j = L >> 3;          // j in [0,128)
  const int nt = j & 7, mtl = j >> 3;         // nt fastest: A-slab reuse
  const int tm = (xcd * 16 + mtl) * 192, tn = nt * 128;
  const int rot2 = (j & 1) * 2048;            // anti-phase: 32 KTs = 2048 elems

  // staging source pointers at k=0 (pre-swizzled global, linear LDS dest)
  const ushort_t* pA[6]; int dA[6];
#pragma unroll
  for (int jj = 0; jj < 6; ++jj) {
    const int q = w * 6 + jj;                 // 0..23
    const int ks = q / 12, rb = q % 12;
    const int row = rb * 16 + (l >> 2);
    const int c = (l & 3) ^ ((row >> 1) & 3);
    pA[jj] = A + (size_t)(tm + row) * 4096 + ks * 32 + c * 8;
    dA[jj] = ks * 12288 + rb * 1024;
  }
  const ushort_t* pB[4]; int dB[4];
#pragma unroll
  for (int jj = 0; jj < 4; ++jj) {
    const int q = w * 4 + jj;                 // 0..15
    const int ks = q >> 3, rb = q & 7;
    const int row = rb * 16 + (l >> 2);
    const int c = (l & 3) ^ ((row >> 1) & 3);
    pB[jj] = Bw + (size_t)(tn + row) * 4096 + ks * 32 + c * 8;
    dB[jj] = P2BOFF + ks * 8192 + rb * 1024;
  }
  int offA = rot2, offB = rot2;               // element offsets, wrap &4095

#define STGA6(BB) do { _Pragma("unroll") for (int jj = 0; jj < 6; ++jj) \
    gld_lds16(pA[jj] + offA, smem + (BB) + dA[jj]); \
    offA = (offA + 64) & 4095; } while (0)
#define STGB4(BB) do { _Pragma("unroll") for (int jj = 0; jj < 4; ++jj) \
    gld_lds16(pB[jj] + offB, smem + (BB) + dB[jj]); \
    offB = (offB + 64) & 4095; } while (0)

  // fragment read bases (swizzled read, conflict-free)
  const int wr = w >> 1, wc = w & 1;          // 2M x 2N
  const int xl = ((l & 15) >> 1) & 3;
  const int cx = ((l >> 4) ^ xl) * 16;
  const int aBase = (wr * 96 + (l & 15)) * 64 + cx;
  const int bBase = P2BOFF + (wc * 64 + (l & 15)) * 64 + cx;

  f32x4 acc[6][4];
  const f32x4 zero = {0.f, 0.f, 0.f, 0.f};
#pragma unroll
  for (int m = 0; m < 6; ++m)
#pragma unroll
    for (int n = 0; n < 4; ++n) acc[m][n] = zero;
  short8 aF[6][2], bF[2][2], bF2[2][2];

#define LDA12(BB) do { _Pragma("unroll") for (int mp = 0; mp < 6; ++mp) { \
    _Pragma("unroll") for (int ks = 0; ks < 2; ++ks) \
      aF[mp][ks] = *(const short8*)(smem + (BB) + ks * 12288 + mp * 1024 + aBase); } } while (0)
#define LDB4(D, BB, NH) do { _Pragma("unroll") for (int np = 0; np < 2; ++np) { \
    _Pragma("unroll") for (int ks = 0; ks < 2; ++ks) \
      D[np][ks] = *(const short8*)(smem + (BB) + ks * 8192 + (NH) * 2048 + np * 1024 + bBase); } } while (0)
#define QUAD24(NH, FB) do { _Pragma("unroll") for (int mp = 0; mp < 6; ++mp) { \
    _Pragma("unroll") for (int np = 0; np < 2; ++np) { \
      _Pragma("unroll") for (int ks = 0; ks < 2; ++ks) \
        acc[mp][(NH)*2+np] = __builtin_amdgcn_mfma_f32_16x16x32_bf16( \
            aF[mp][ks], FB[np][ks], acc[mp][(NH)*2+np], 0, 0, 0); } } } while (0)
#define BARR do { __builtin_amdgcn_s_barrier(); asm volatile("" ::: "memory"); } while (0)
#define WAITV(N) do { asm volatile("s_waitcnt vmcnt(" #N ")" ::: "memory"); \
    __builtin_amdgcn_sched_barrier(0); } while (0)
#define PRIO1 __builtin_amdgcn_s_setprio(1)
#define PRIO0 __builtin_amdgcn_s_setprio(0)

  // prologue: KT(s) -> buf0 (A+B); KT(s+1).A -> buf1; drain KT(s)
  STGA6(0); STGB4(0);
  STGA6(P2BUF);
  WAITV(6);
  BARR;

  const int nit2 = 32;                         // 64 KTs, 2 per iteration
  for (int t2 = 0; t2 < nit2; ++t2) {
    const bool morA = (t2 + 1 < nit2);
    // ---- KT even (buf0) ----
    LDA12(0); LDB4(bF, 0, 0); LDB4(bF2, 0, 1);
    STGB4(P2BUF);                              // B(t+1) -> buf1
    PRIO1; QUAD24(0, bF); PRIO0;
    BARR;                                      // seals all waves' buf0 reads
    if (morA) STGA6(0);                        // A(t+2) -> buf0
    PRIO1; QUAD24(1, bF2); PRIO0;
    if (morA) { WAITV(6); } else { WAITV(0); } // drain KT(t+1) data
    BARR;
    // ---- KT odd (buf1) ----
    LDA12(P2BUF); LDB4(bF, P2BUF, 0); LDB4(bF2, P2BUF, 1);
    if (morA) STGB4(0);                        // B(t+2) -> buf0
    PRIO1; QUAD24(0, bF); PRIO0;
    BARR;
    if (morA) STGA6(P2BUF);                    // A(t+3) -> buf1
    PRIO1; QUAD24(1, bF2); PRIO0;
    if (morA) { WAITV(6); } else { WAITV(0); }
    BARR;
  }

  // ---- epilogue: out += acc + bias (single writer, no atomics) ----
  float bv[4];
#pragma unroll
  for (int n = 0; n < 4; ++n)
    bv[n] = bias[tn + wc * 64 + (n >> 1) * 32 + (n & 1) * 16 + (l & 15)];
#pragma unroll
  for (int m = 0; m < 6; ++m) {
    const int row = tm + wr * 96 + m * 16 + (l >> 4) * 4;
#pragma unroll
    for (int n = 0; n < 4; ++n) {
      const int col = tn + wc * 64 + (n >> 1) * 32 + (n & 1) * 16 + (l & 15);
      float* po = outp + (size_t)row * EMBED + col;
#pragma unroll
      for (int ri = 0; ri < 4; ++ri)
        po[(size_t)ri * EMBED] += acc[m][n][ri] + bv[n];
    }
  }
}

// ---- launch -------------------------------------------------------------

extern "C" void kernel_launch(void* const* d_in, const int* in_sizes, int n_in,
                              void* d_out, int out_size, void* d_ws, size_t ws_size,
                              hipStream_t stream) {
  const float* xg[3] = {(const float*)d_in[0], (const float*)d_in[3], (const float*)d_in[6]};
  const float* mg[3] = {(const float*)d_in[1], (const float*)d_in[4], (const float*)d_in[7]};
  const float* tg[3] = {(const float*)d_in[2], (const float*)d_in[5], (const float*)d_in[8]};
  const int* idxg[3] = {(const int*)d_in[9], (const int*)d_in[10], (const int*)d_in[11]};
  const float* W_lin = (const float*)d_in[12];
  const float* b_lin = (const float*)d_in[13];
  const float* W_res = (const float*)d_in[14];
  const float* b_res = (const float*)d_in[15];
  const float* W_out = (const float*)d_in[16];
  const float* b_out = (const float*)d_in[17];
  float* out = (float*)d_out;

  char* ws = (char*)d_ws;
  size_t off = 0;
  auto alloc = [&](size_t b) -> char* {
    size_t o = (off + 255) & ~(size_t)255;
    off = o + b;
    return ws + o;
  };

  ushort_t* hidden = (ushort_t*)alloc((size_t)MROWS * INTER * 2);   // 201 MB
  const int Kp[3] = {64, 96, 192};
  ushort_t* xsw[3];
  ushort_t* wcat[3];
  for (int g = 0; g < 3; ++g) xsw[g]  = (ushort_t*)alloc((size_t)8192 * Kp[g] * 2);
  for (int g = 0; g < 3; ++g) wcat[g] = (ushort_t*)alloc((size_t)NCAT * Kp[g] * 2);
  ushort_t* wout = (ushort_t*)alloc((size_t)EMBED * INTER * 2);     // 8 MB
  float* bcat = (float*)alloc((size_t)NCAT * 4);

  // merged preps: 2 dispatches
  const int wTotal = NCAT + EMBED * INTER + NCAT * 352;   // 6,001,664
  prep_w<<<(wTotal + 255) / 256, 256, 0, stream>>>(
      W_lin, W_res, W_out, b_lin, b_res, wout, wcat[0], wcat[1], wcat[2], bcat);
  const int xTotal = 8192 * 352;                          // 2,883,584
  prep_x<<<(xTotal + 255) / 256, 256, 0, stream>>>(
      xg[0], mg[0], tg[0], xg[1], mg[1], tg[1], xg[2], mg[2], tg[2],
      xsw[0], xsw[1], xsw[2]);

  // phase 1: all 3 groups in ONE dispatch: [8192 x Kp] @ [5120 x Kp]^T each
  gemm128p1g<<<dim3(192, 40), 256, 0, stream>>>(
      xsw[0], xsw[1], xsw[2], wcat[0], wcat[1], wcat[2], bcat,
      hidden, out, idxg[0], idxg[1], idxg[2]);
  // phase 2: [24576 x 4096] @ [1024 x 4096]^T, full K, out += acc + b_out
  gemm192x128<<<dim3(1024), 256, 0, stream>>>(hidden, wout, b_out, out);
}